// Round 15
// baseline (464.648 us; speedup 1.0000x reference)
//
#include <hip/hip_runtime.h>
#include <hip/hip_bf16.h>
#include <math.h>

#define Bn 256
#define Tn 64
#define OBSD 1000
#define NR 30
#define HD 128
#define LH 256
#define LIN 384
#define TDI 26

#define AM_OFF 0
#define ALS_OFF 15360
#define V_OFF 30720
#define H_OFF 30976
#define C_OFF 96512

typedef unsigned short u16;
typedef short bf16x8 __attribute__((ext_vector_type(8)));
typedef float f32x4 __attribute__((ext_vector_type(4)));

__device__ __forceinline__ float sigm(float x){ return 1.f/(1.f+__expf(-x)); }
__device__ __forceinline__ float tanhfast(float x){
    float ax = fabsf(x);
    float e = __expf(2.f*ax);
    float t = 1.f - 2.f/(e+1.f);
    return copysignf(t, x);
}

__device__ __forceinline__ u16 f2b(float f){
    union { __hip_bfloat16 h; u16 u; } cv;
    cv.h = __float2bfloat16(f);
    return cv.u;
}

// system-coherent (L3) access helpers — proven r5 protocol
__device__ __forceinline__ bf16x8 ld_b128_sys(const u16* p){
    bf16x8 r;
    asm volatile("global_load_dwordx4 %0, %1, off sc0 sc1"
                 : "=v"(r) : "v"(p) : "memory");
    return r;
}
__device__ __forceinline__ void st_b16_sys(u16* p, unsigned v){
    asm volatile("global_store_short %0, %1, off sc0 sc1"
                 :: "v"(p), "v"(v) : "memory");
}

#define MFMA(a,b,c) __builtin_amdgcn_mfma_f32_16x16x32_bf16(a,b,c,0,0,0)

// ---------------- fused setup kernel (packs + dtv + flags) ----------------
__device__ __forceinline__ void pack_one(
    const float* __restrict__ src, u16* __restrict__ dst,
    int N, int K, int Kpad, int t)
{
    if (t >= N*Kpad) return;
    int j = t / Kpad, k = t - j*Kpad;
    float v = (k < K) ? src[j*K + k] : 0.f;
    int ntile = j>>4, jr = j&15, kc = k>>5, ko = k&31;
    int lane = ((ko>>3)<<4) | jr, elem = ko&7;
    int KC = Kpad>>5;
    dst[(size_t)(((ntile*KC + kc)*64) + lane)*8 + elem] = f2b(v);
}

__device__ __forceinline__ void pack_gi_one(
    const float* __restrict__ src, u16* __restrict__ dst, int K, int t)
{
    int KC = K >> 5;
    if (t >= 1024*K) return;
    int n = t / K, k = t - n*K;
    int nt = n>>4, jr = n&15;
    int jg = nt>>2, g = nt&3;
    float v = src[(size_t)(g*256 + jg*16 + jr)*K + k];
    int kc = k>>5, ko = k&31;
    int lane = ((ko>>3)<<4) | jr, e = ko&7;
    dst[(size_t)(((nt*KC + kc)*64) + lane)*8 + e] = f2b(v);
}

__global__ __launch_bounds__(256) void k_setup(
    const float* __restrict__ re_w0, u16* __restrict__ pw0,
    const float* __restrict__ re_w1, u16* __restrict__ pw1,
    const float* __restrict__ re_w2, u16* __restrict__ pw2,
    const float* __restrict__ me_w0, u16* __restrict__ pm0,
    const float* __restrict__ me_w1, u16* __restrict__ pm1,
    const float* __restrict__ me_w2, u16* __restrict__ pm2,
    const float* __restrict__ W_ih,  u16* __restrict__ pwih,
    const float* __restrict__ W_hh,  u16* __restrict__ pwhh,
    const float* __restrict__ obs,   float* __restrict__ dtv,
    unsigned int* __restrict__ flags)
{
    int blk = blockIdx.x, tid = threadIdx.x;
    if (blk < 16){            pack_one(re_w0, pw0, 128, 32, 32,  blk*256 + tid); }
    else if (blk < 80){       pack_one(re_w1, pw1, 128,128,128, (blk-16)*256 + tid); }
    else if (blk < 144){      pack_one(re_w2, pw2, 128,128,128, (blk-80)*256 + tid); }
    else if (blk < 176){      pack_one(me_w0, pm0, 128, 40, 64, (blk-144)*256 + tid); }
    else if (blk < 240){      pack_one(me_w1, pm1, 128,128,128, (blk-176)*256 + tid); }
    else if (blk < 304){      pack_one(me_w2, pm2, 128,128,128, (blk-240)*256 + tid); }
    else if (blk < 1840){     pack_gi_one(W_ih, pwih, 384, (blk-304)*256 + tid); }
    else if (blk < 2864){     pack_gi_one(W_hh, pwhh, 256, (blk-1840)*256 + tid); }
    else if (blk < 2928){
        int idx = (blk-2864)*256 + tid;      // 16384
        int b = idx >> 6, t = idx & 63;
        dtv[t*256 + b] = obs[(size_t)idx*OBSD + TDI];
    } else {
        flags[(blk-2928)*256 + tid] = 0u;    // 2048 entries
    }
}

// ---------------- fused embed (4 bt/block, M=128) + market (32 rows/block) ----------------
// blocks [0,4096): runner embed; [4096,4608): market embed
__global__ __launch_bounds__(256) void k_embed_market(
    const float* __restrict__ obs,
    const u16* __restrict__ pw0, const float* __restrict__ re_b0,
    const u16* __restrict__ pw1, const float* __restrict__ re_b1,
    const u16* __restrict__ pw2, const float* __restrict__ re_b2,
    const u16* __restrict__ pm0, const float* __restrict__ me_b0,
    const u16* __restrict__ pm1, const float* __restrict__ me_b1,
    const u16* __restrict__ pm2, const float* __restrict__ me_b2,
    u16* __restrict__ li_bf, float* __restrict__ runner_last)
{
    __shared__ __align__(16) u16 smem[22528];   // embed: xr 5120 + act 17408; market: 11008
    __shared__ float bsf[384];

    int blk = blockIdx.x, tid = threadIdx.x;
    int lane = tid & 63, wv = tid >> 6;
    int lr = lane & 15, lk = lane >> 4;
    f32x4 zero = {0.f,0.f,0.f,0.f};

    if (blk < 4096){
        // ================= runner embed, 4 bt, M=128 =================
        u16* xr  = smem;            // 128*40
        u16* act = smem + 5120;     // 128*136 (reused for L0-out then L1-out)
        float* bs0 = bsf, *bs1 = bsf+128, *bs2 = bsf+256;

        int bt0 = blk*4;

        for (int idx=tid; idx<4096; idx+=256){
            int r = idx>>5, k = idx&31;
            int sb = r>>5, rr = r&31;
            const float* row = obs + (size_t)(bt0+sb)*OBSD;
            float v = 0.f;
            if (rr < 30) v = (k<24) ? row[30 + rr*24 + k] : row[760 + rr*8 + (k-24)];
            xr[r*40 + k] = f2b(v);
        }
        if (tid < 128){ bs0[tid]=re_b0[tid]; bs1[tid]=re_b1[tid]; bs2[tid]=re_b2[tid]; }
        __syncthreads();

        f32x4 d[8][2];

        // ---- layer 0 (K=32) ----
        {
            bf16x8 a0[8];
            #pragma unroll
            for (int m=0;m<8;m++) a0[m] = *(const bf16x8*)(xr + (m*16+lr)*40 + lk*8);
            #pragma unroll
            for (int ns=0; ns<2; ns++){
                int n = 2*wv + ns;
                bf16x8 b = *(const bf16x8*)(pw0 + (size_t)(n*64 + lane)*8);
                #pragma unroll
                for (int m=0;m<8;m++) d[m][ns] = MFMA(a0[m], b, zero);
            }
        }
        #pragma unroll
        for (int m=0;m<8;m++)
            #pragma unroll
            for (int ns=0;ns<2;ns++){
                int col = (2*wv+ns)*16 + lr;
                float bias = bs0[col];
                #pragma unroll
                for (int r=0;r<4;r++)
                    act[(m*16+lk*4+r)*136 + col] = f2b(fmaxf(d[m][ns][r] + bias, 0.f));
            }
        __syncthreads();

        // ---- layer 1 (K=128): read act fully, then overwrite in place ----
        #pragma unroll
        for (int m=0;m<8;m++)
            #pragma unroll
            for (int ns=0;ns<2;ns++) d[m][ns] = zero;
        #pragma unroll
        for (int kc=0; kc<4; kc++){
            bf16x8 am[8];
            #pragma unroll
            for (int m=0;m<8;m++) am[m] = *(const bf16x8*)(act + (m*16+lr)*136 + kc*32 + lk*8);
            #pragma unroll
            for (int ns=0; ns<2; ns++){
                int n = 2*wv + ns;
                bf16x8 b = *(const bf16x8*)(pw1 + (size_t)((n*4 + kc)*64 + lane)*8);
                #pragma unroll
                for (int m=0;m<8;m++) d[m][ns] = MFMA(am[m], b, d[m][ns]);
            }
        }
        __syncthreads();   // all L1 reads of act complete
        #pragma unroll
        for (int m=0;m<8;m++)
            #pragma unroll
            for (int ns=0;ns<2;ns++){
                int col = (2*wv+ns)*16 + lr;
                float bias = bs1[col];
                #pragma unroll
                for (int r=0;r<4;r++)
                    act[(m*16+lk*4+r)*136 + col] = f2b(fmaxf(d[m][ns][r] + bias, 0.f));
            }
        __syncthreads();

        // ---- layer 2 (K=128, no relu) + reductions ----
        #pragma unroll
        for (int m=0;m<8;m++)
            #pragma unroll
            for (int ns=0;ns<2;ns++) d[m][ns] = zero;
        #pragma unroll
        for (int kc=0; kc<4; kc++){
            bf16x8 am[8];
            #pragma unroll
            for (int m=0;m<8;m++) am[m] = *(const bf16x8*)(act + (m*16+lr)*136 + kc*32 + lk*8);
            #pragma unroll
            for (int ns=0; ns<2; ns++){
                int n = 2*wv + ns;
                bf16x8 b = *(const bf16x8*)(pw2 + (size_t)((n*4 + kc)*64 + lane)*8);
                #pragma unroll
                for (int m=0;m<8;m++) d[m][ns] = MFMA(am[m], b, d[m][ns]);
            }
        }

        bool last3 = (((bt0+3) & 63) == 63);
        int bb3 = (bt0+3) >> 6;

        #pragma unroll
        for (int ns=0; ns<2; ns++){
            int col = (2*wv+ns)*16 + lr;
            float bias = bs2[col];
            float vals[8][4];
            float ss0=0.f, ss1=0.f, ss2=0.f, ss3=0.f;
            float mm0=-3.4e38f, mm1=-3.4e38f, mm2=-3.4e38f, mm3=-3.4e38f;
            #pragma unroll
            for (int m=0;m<8;m++)
                #pragma unroll
                for (int r=0;r<4;r++){
                    int rw = m*16 + lk*4 + r;
                    float v = d[m][ns][r] + bias;
                    vals[m][r] = v;
                    int sb = m >> 1;
                    bool ok = (rw - sb*32) < 30;
                    float va = ok ? v : 0.f;
                    float vm = ok ? v : -3.4e38f;
                    if (sb == 0){ ss0 += va; mm0 = fmaxf(mm0, vm); }
                    else if (sb == 1){ ss1 += va; mm1 = fmaxf(mm1, vm); }
                    else if (sb == 2){ ss2 += va; mm2 = fmaxf(mm2, vm); }
                    else { ss3 += va; mm3 = fmaxf(mm3, vm); }
                }
            ss0 += __shfl_xor(ss0, 16); ss0 += __shfl_xor(ss0, 32);
            mm0 = fmaxf(mm0, __shfl_xor(mm0, 16)); mm0 = fmaxf(mm0, __shfl_xor(mm0, 32));
            ss1 += __shfl_xor(ss1, 16); ss1 += __shfl_xor(ss1, 32);
            mm1 = fmaxf(mm1, __shfl_xor(mm1, 16)); mm1 = fmaxf(mm1, __shfl_xor(mm1, 32));
            ss2 += __shfl_xor(ss2, 16); ss2 += __shfl_xor(ss2, 32);
            mm2 = fmaxf(mm2, __shfl_xor(mm2, 16)); mm2 = fmaxf(mm2, __shfl_xor(mm2, 32));
            ss3 += __shfl_xor(ss3, 16); ss3 += __shfl_xor(ss3, 32);
            mm3 = fmaxf(mm3, __shfl_xor(mm3, 16)); mm3 = fmaxf(mm3, __shfl_xor(mm3, 32));
            if (lk == 0){
                u16* li = li_bf + (size_t)(bt0+0)*LIN;
                li[128 + col] = f2b(ss0 * (1.0f/30.0f));
                li[256 + col] = f2b(mm0);
            } else if (lk == 1){
                u16* li = li_bf + (size_t)(bt0+1)*LIN;
                li[128 + col] = f2b(ss1 * (1.0f/30.0f));
                li[256 + col] = f2b(mm1);
            } else if (lk == 2){
                u16* li = li_bf + (size_t)(bt0+2)*LIN;
                li[128 + col] = f2b(ss2 * (1.0f/30.0f));
                li[256 + col] = f2b(mm2);
            } else {
                u16* li = li_bf + (size_t)(bt0+3)*LIN;
                li[128 + col] = f2b(ss3 * (1.0f/30.0f));
                li[256 + col] = f2b(mm3);
            }
            if (last3){
                #pragma unroll
                for (int m=6;m<8;m++)
                    #pragma unroll
                    for (int r=0;r<4;r++){
                        int rwl = m*16 + lk*4 + r - 96;
                        if (rwl < 30) runner_last[(size_t)bb3*3840 + rwl*128 + col] = vals[m][r];
                    }
            }
        }
    } else {
        // ================= market embed =================
        u16* xm  = smem;            // 32*72
        u16* ma1 = smem + 2304;     // 32*136
        u16* ma2 = smem + 6656;     // 32*136
        float* bs0 = bsf, *bs1 = bsf+128, *bs2 = bsf+256;

        int bt0 = (blk - 4096)*32;
        for (int idx=tid; idx<2048; idx+=256){
            int r = idx>>6, k = idx&63;
            const float* row = obs + (size_t)(bt0+r)*OBSD;
            float v = 0.f;
            if (k < 30) v = row[k];
            else if (k < 40) v = row[720 + k];
            xm[r*72 + k] = f2b(v);
        }
        if (tid < 128){ bs0[tid]=me_b0[tid]; bs1[tid]=me_b1[tid]; bs2[tid]=me_b2[tid]; }
        __syncthreads();

        f32x4 d[2][2];

        #pragma unroll
        for (int m=0;m<2;m++)
            #pragma unroll
            for (int ns=0;ns<2;ns++) d[m][ns] = zero;
        #pragma unroll
        for (int kc=0; kc<2; kc++){
            bf16x8 a0 = *(const bf16x8*)(xm + lr*72      + kc*32 + lk*8);
            bf16x8 a1 = *(const bf16x8*)(xm + (16+lr)*72 + kc*32 + lk*8);
            #pragma unroll
            for (int ns=0; ns<2; ns++){
                int n = 2*wv + ns;
                bf16x8 b = *(const bf16x8*)(pm0 + (size_t)((n*2 + kc)*64 + lane)*8);
                d[0][ns] = MFMA(a0, b, d[0][ns]);
                d[1][ns] = MFMA(a1, b, d[1][ns]);
            }
        }
        #pragma unroll
        for (int m=0;m<2;m++)
            #pragma unroll
            for (int ns=0;ns<2;ns++){
                int col = (2*wv+ns)*16 + lr;
                float bias = bs0[col];
                #pragma unroll
                for (int r=0;r<4;r++){
                    int rw = m*16 + lk*4 + r;
                    ma1[rw*136 + col] = f2b(fmaxf(d[m][ns][r] + bias, 0.f));
                }
            }
        __syncthreads();

        #pragma unroll
        for (int m=0;m<2;m++)
            #pragma unroll
            for (int ns=0;ns<2;ns++) d[m][ns] = zero;
        #pragma unroll
        for (int kc=0; kc<4; kc++){
            bf16x8 a0 = *(const bf16x8*)(ma1 + lr*136      + kc*32 + lk*8);
            bf16x8 a1 = *(const bf16x8*)(ma1 + (16+lr)*136 + kc*32 + lk*8);
            #pragma unroll
            for (int ns=0; ns<2; ns++){
                int n = 2*wv + ns;
                bf16x8 b = *(const bf16x8*)(pm1 + (size_t)((n*4 + kc)*64 + lane)*8);
                d[0][ns] = MFMA(a0, b, d[0][ns]);
                d[1][ns] = MFMA(a1, b, d[1][ns]);
            }
        }
        #pragma unroll
        for (int m=0;m<2;m++)
            #pragma unroll
            for (int ns=0;ns<2;ns++){
                int col = (2*wv+ns)*16 + lr;
                float bias = bs1[col];
                #pragma unroll
                for (int r=0;r<4;r++){
                    int rw = m*16 + lk*4 + r;
                    ma2[rw*136 + col] = f2b(fmaxf(d[m][ns][r] + bias, 0.f));
                }
            }
        __syncthreads();

        #pragma unroll
        for (int m=0;m<2;m++)
            #pragma unroll
            for (int ns=0;ns<2;ns++) d[m][ns] = zero;
        #pragma unroll
        for (int kc=0; kc<4; kc++){
            bf16x8 a0 = *(const bf16x8*)(ma2 + lr*136      + kc*32 + lk*8);
            bf16x8 a1 = *(const bf16x8*)(ma2 + (16+lr)*136 + kc*32 + lk*8);
            #pragma unroll
            for (int ns=0; ns<2; ns++){
                int n = 2*wv + ns;
                bf16x8 b = *(const bf16x8*)(pm2 + (size_t)((n*4 + kc)*64 + lane)*8);
                d[0][ns] = MFMA(a0, b, d[0][ns]);
                d[1][ns] = MFMA(a1, b, d[1][ns]);
            }
        }
        #pragma unroll
        for (int m=0;m<2;m++)
            #pragma unroll
            for (int ns=0;ns<2;ns++){
                int col = (2*wv+ns)*16 + lr;
                float bias = bs2[col];
                #pragma unroll
                for (int r=0;r<4;r++){
                    int rw = m*16 + lk*4 + r;
                    li_bf[(size_t)(bt0+rw)*LIN + col] = f2b(d[m][ns][r] + bias);
                }
            }
    }
}

// ---------------- xW precompute (MFMA), LDS-shared B panel ----------------
// Output layout: xw[(t*256 + b)*256 + jg*16+lr] as float4 {g0,g1,g2,g3}
__global__ __launch_bounds__(256) void k_xw(
    const u16* __restrict__ A, const u16* __restrict__ pwih,
    const float* __restrict__ b_ih, float* __restrict__ xw)
{
    __shared__ __align__(16) u16 bsh[48*512];   // 48 KB

    int tid = threadIdx.x;
    int lane = tid & 63, wv = tid >> 6;
    int lr = lane & 15, lk = lane >> 4;
    int r0 = blockIdx.x*128 + wv*32;

    bf16x8 a[2][12];
    #pragma unroll
    for (int m=0;m<2;m++)
        #pragma unroll
        for (int kc=0;kc<12;kc++)
            a[m][kc] = *(const bf16x8*)(A + (size_t)(r0+m*16+lr)*384 + kc*32 + lk*8);

    for (int jg=0; jg<16; jg++){
        {
            const bf16x8* src = (const bf16x8*)(pwih + (size_t)jg*48*512);
            bf16x8* dst = (bf16x8*)bsh;
            #pragma unroll
            for (int i=0;i<12;i++)
                dst[tid + i*256] = src[tid + i*256];
        }
        __syncthreads();

        f32x4 acc[2][4];
        #pragma unroll
        for (int g=0; g<4; g++){
            float bias = b_ih[g*256 + jg*16 + lr];
            f32x4 v = {bias,bias,bias,bias};
            acc[0][g]=v; acc[1][g]=v;
        }
        #pragma unroll
        for (int kc=0; kc<12; kc++){
            bf16x8 b0 = *(const bf16x8*)(bsh + (size_t)((0*12+kc)*64+lane)*8);
            bf16x8 b1 = *(const bf16x8*)(bsh + (size_t)((1*12+kc)*64+lane)*8);
            bf16x8 b2 = *(const bf16x8*)(bsh + (size_t)((2*12+kc)*64+lane)*8);
            bf16x8 b3 = *(const bf16x8*)(bsh + (size_t)((3*12+kc)*64+lane)*8);
            #pragma unroll
            for (int m=0;m<2;m++){
                acc[m][0] = MFMA(a[m][kc], b0, acc[m][0]);
                acc[m][1] = MFMA(a[m][kc], b1, acc[m][1]);
                acc[m][2] = MFMA(a[m][kc], b2, acc[m][2]);
                acc[m][3] = MFMA(a[m][kc], b3, acc[m][3]);
            }
        }
        #pragma unroll
        for (int m=0;m<2;m++)
            #pragma unroll
            for (int r=0;r<4;r++){
                int row = r0 + m*16 + lk*4 + r;       // bt index (b*64+t)
                int trow = (row & 63)*256 + (row >> 6);
                float4 pk;
                pk.x = acc[m][0][r]; pk.y = acc[m][1][r];
                pk.z = acc[m][2][r]; pk.w = acc[m][3][r];
                *(float4*)(xw + ((size_t)trow*256 + jg*16 + lr)*4) = pk;
            }
        __syncthreads();
    }
}

// ---------------- pairwise persistent LSTM (r11-green protocol; acc-init hoisted) ----------------
__global__ __launch_bounds__(256,1) void k_lstm_pair(
    const float* __restrict__ xw, const u16* __restrict__ pwhh,
    const float* __restrict__ W_dt, const float* __restrict__ dtv,
    u16* __restrict__ hb0, u16* __restrict__ hb1,
    float* __restrict__ hout, float* __restrict__ cout,
    unsigned int* __restrict__ flags)
{
    int tid = threadIdx.x;
    int lane = tid & 63, wv = tid >> 6;
    int lr = lane & 15, lk = lane >> 4;
    int blk = blockIdx.x;
    int p = blk >> 1, hf = blk & 1;
    int bb0 = p*16;
    int jg0 = hf*8 + wv*2;

    bf16x8 bfr[2][4][8];
    #pragma unroll
    for (int jl=0;jl<2;jl++)
        #pragma unroll
        for (int g=0;g<4;g++)
            #pragma unroll
            for (int kc=0;kc<8;kc++)
                bfr[jl][g][kc] = *(const bf16x8*)(pwhh + (size_t)((((jg0+jl)*4+g)*8+kc)*64+lane)*8);

    float wdt0 = W_dt[jg0*16 + lr];
    float wdt1 = W_dt[(jg0+1)*16 + lr];

    float cst[2][4] = {{0.f,0.f,0.f,0.f},{0.f,0.f,0.f,0.f}};
    bf16x8 a[8];
    #pragma unroll
    for (int kc=0;kc<8;kc++) a[kc] = (bf16x8)(short)0;

    int bth = bb0 + lk*4;

    float4 xwn[2][4];
    #pragma unroll
    for (int jl=0;jl<2;jl++)
        #pragma unroll
        for (int r=0;r<4;r++)
            xwn[jl][r] = *(const float4*)(xw + ((size_t)(bth+r)*256 + (jg0+jl)*16 + lr)*4);
    float4 dtn = *(const float4*)(dtv + bth);

    // acc for t=0 (built from xwn in prologue)
    f32x4 acc[2][4];
    #pragma unroll
    for (int jl=0;jl<2;jl++){
        f32x4 v0, v1, v2, v3;
        #pragma unroll
        for (int r=0;r<4;r++){
            v0[r] = xwn[jl][r].x; v1[r] = xwn[jl][r].y;
            v2[r] = xwn[jl][r].z; v3[r] = xwn[jl][r].w;
        }
        acc[jl][0] = v0; acc[jl][1] = v1; acc[jl][2] = v2; acc[jl][3] = v3;
    }

    unsigned int* myflag   = &flags[blk*64];
    unsigned int* partflag = &flags[(blk^1)*64];

    for (int t=0; t<64; t++){
        // a[] (inline-asm loads) must be complete before MFMA
        asm volatile("s_waitcnt vmcnt(0)" ::: "memory");
        __builtin_amdgcn_sched_barrier(0);

        #pragma unroll
        for (int kc=0; kc<8; kc++){
            #pragma unroll
            for (int jl=0;jl<2;jl++){
                acc[jl][0] = MFMA(a[kc], bfr[jl][0][kc], acc[jl][0]);
                acc[jl][1] = MFMA(a[kc], bfr[jl][1][kc], acc[jl][1]);
                acc[jl][2] = MFMA(a[kc], bfr[jl][2][kc], acc[jl][2]);
                acc[jl][3] = MFMA(a[kc], bfr[jl][3][kc], acc[jl][3]);
            }
        }

        u16* hw = (t&1) ? hb1 : hb0;
        #pragma unroll
        for (int jl=0;jl<2;jl++){
            float wdt = jl ? wdt1 : wdt0;
            int jcol = (jg0+jl)*16 + lr;
            #pragma unroll
            for (int r=0;r<4;r++){
                float dd = (r==0)?dtn.x:(r==1)?dtn.y:(r==2)?dtn.z:dtn.w;
                float gi = sigm(acc[jl][0][r]);
                float gf = sigm(acc[jl][1][r] + wdt*dd);
                float gg = tanhfast(acc[jl][2][r]);
                float go = sigm(acc[jl][3][r]);
                float cn = fmaf(gf, cst[jl][r], gi*gg);
                cst[jl][r] = cn;
                float hv = go * tanhfast(cn);
                if (t < 63){
                    st_b16_sys(hw + (size_t)(bth+r)*256 + jcol, (unsigned)f2b(hv));
                } else {
                    hout[(size_t)(bth+r)*256 + jcol] = hv;
                    cout[(size_t)(bth+r)*256 + jcol] = cn;
                }
            }
        }

        if (t < 63){
            // own h slice visible at L3 before flag
            asm volatile("s_waitcnt vmcnt(0)" ::: "memory");
            __syncthreads();
            if (tid == 0)
                __hip_atomic_store(myflag, (unsigned)(t+1),
                                   __ATOMIC_RELAXED, __HIP_MEMORY_SCOPE_SYSTEM);

            // prefetch next xw/dt (plain cached loads; overlap the poll)
            #pragma unroll
            for (int jl=0;jl<2;jl++)
                #pragma unroll
                for (int r=0;r<4;r++)
                    xwn[jl][r] = *(const float4*)(xw + ((size_t)((t+1)*256 + bth+r)*256 + (jg0+jl)*16 + lr)*4);
            dtn = *(const float4*)(dtv + (t+1)*256 + bth);

            if (lane == 0){
                while (__hip_atomic_load(partflag, __ATOMIC_RELAXED,
                                         __HIP_MEMORY_SCOPE_SYSTEM) < (unsigned)(t+1)) {}
            }
            __builtin_amdgcn_wave_barrier();

            const u16* hr = (t&1) ? hb1 : hb0;
            #pragma unroll
            for (int kc=0; kc<8; kc++)
                a[kc] = ld_b128_sys(hr + (size_t)(bb0+lr)*256 + kc*32 + lk*8);

            // build acc for t+1 in the h-load shadow (xwn complete: poll's
            // value-use drained all older loads)
            #pragma unroll
            for (int jl=0;jl<2;jl++){
                f32x4 v0, v1, v2, v3;
                #pragma unroll
                for (int r=0;r<4;r++){
                    v0[r] = xwn[jl][r].x; v1[r] = xwn[jl][r].y;
                    v2[r] = xwn[jl][r].z; v3[r] = xwn[jl][r].w;
                }
                acc[jl][0] = v0; acc[jl][1] = v1; acc[jl][2] = v2; acc[jl][3] = v3;
            }
        }
    }
}

// ---------------- heads (fp32) ----------------
__device__ __forceinline__ void dense30(
    const float* in, int istride,
    const float* __restrict__ W, int wstride, int K,
    const float* __restrict__ bias, const float* extra,
    float* outp, int ostride, bool relu, int j, int rh)
{
    float acc[15];
    #pragma unroll
    for (int i=0;i<15;i++) acc[i]=0.f;
    const float* w = W + j*wstride;
    for (int k=0;k<K;k+=4){
        float4 wv = *(const float4*)(w+k);
        #pragma unroll
        for (int i=0;i<15;i++){
            float4 xv = *(const float4*)(in + (rh+2*i)*istride + k);
            acc[i] = fmaf(wv.x,xv.x,acc[i]);
            acc[i] = fmaf(wv.y,xv.y,acc[i]);
            acc[i] = fmaf(wv.z,xv.z,acc[i]);
            acc[i] = fmaf(wv.w,xv.w,acc[i]);
        }
    }
    float bb = bias[j] + (extra ? extra[j] : 0.f);
    #pragma unroll
    for (int i=0;i<15;i++){
        float v = acc[i]+bb;
        outp[(rh+2*i)*ostride+j] = relu ? fmaxf(v,0.f) : v;
    }
}

__device__ __forceinline__ float dense1(
    const float* in, const float* __restrict__ W,
    const float* __restrict__ bias, int K, int j)
{
    const float* w = W + j*K;
    float s = 0.f;
    for (int k=0;k<K;k+=4){
        float4 wv = *(const float4*)(w+k);
        float4 xv = *(const float4*)(in+k);
        s = fmaf(wv.x,xv.x,s); s = fmaf(wv.y,xv.y,s);
        s = fmaf(wv.z,xv.z,s); s = fmaf(wv.w,xv.w,s);
    }
    return s + bias[j];
}

__global__ __launch_bounds__(256) void k_heads(
    const float* __restrict__ h, const float* __restrict__ cbuf,
    const float* __restrict__ rl,
    const float* __restrict__ a_w0, const float* __restrict__ a_b0,
    const float* __restrict__ a_w1, const float* __restrict__ a_b1,
    const float* __restrict__ c_w0, const float* __restrict__ c_b0,
    const float* __restrict__ c_w1, const float* __restrict__ c_b1,
    const float* __restrict__ log_std,
    float* __restrict__ out)
{
    __shared__ __align__(16) float hv[LH];
    __shared__ __align__(16) float rls[NR][HD];
    __shared__ __align__(16) float hid[NR][HD];
    __shared__ __align__(16) float dot2[HD];
    __shared__ __align__(16) float red[128];

    int b = blockIdx.x, tid = threadIdx.x;
    hv[tid] = h[b*LH + tid];
    for (int idx=tid; idx<NR*HD; idx+=256) rls[idx>>7][idx&127] = rl[(size_t)b*NR*HD + idx];
    __syncthreads();

    if (tid < 128){
        const float* w = a_w0 + tid*LIN + HD;
        float s = 0.f;
        for (int k=0;k<LH;k+=4){
            float4 wv = *(const float4*)(w+k);
            s = fmaf(wv.x,hv[k],s); s = fmaf(wv.y,hv[k+1],s);
            s = fmaf(wv.z,hv[k+2],s); s = fmaf(wv.w,hv[k+3],s);
        }
        dot2[tid] = s;
    }
    __syncthreads();

    int j = tid & 127, rh = tid >> 7;
    dense30(&rls[0][0], HD, a_w0, LIN, HD, a_b0, dot2, &hid[0][0], HD, true, j, rh);
    __syncthreads();

    if (tid < 60){
        int r = tid >> 1, o = tid & 1;
        const float* w = a_w1 + o*HD;
        float s = a_b1[o];
        for (int k=0;k<HD;k++) s = fmaf(hid[r][k], w[k], s);
        out[AM_OFF + b*60 + tid] = s;
        out[ALS_OFF + b*60 + tid] = log_std[tid];
    }

    float term = 0.f;
    if (tid < 128) term = fmaxf(dense1(hv, c_w0, c_b0, LH, tid), 0.f) * c_w1[tid];
    if (tid < 128) red[tid] = term;
    __syncthreads();
    for (int s2=64; s2>0; s2>>=1){
        if (tid < s2) red[tid] += red[tid+s2];
        __syncthreads();
    }
    if (tid == 0) out[V_OFF + b] = red[0] + c_b1[0];

    out[H_OFF + b*LH + tid] = hv[tid];
    out[C_OFF + b*LH + tid] = cbuf[b*LH + tid];
}

extern "C" void kernel_launch(void* const* d_in, const int* in_sizes, int n_in,
                              void* d_out, int out_size, void* d_ws, size_t ws_size,
                              hipStream_t stream)
{
    const float* obs   = (const float*)d_in[0];
    const float* re_w0 = (const float*)d_in[1];
    const float* re_b0 = (const float*)d_in[2];
    const float* re_w1 = (const float*)d_in[3];
    const float* re_b1 = (const float*)d_in[4];
    const float* re_w2 = (const float*)d_in[5];
    const float* re_b2 = (const float*)d_in[6];
    const float* me_w0 = (const float*)d_in[7];
    const float* me_b0 = (const float*)d_in[8];
    const float* me_w1 = (const float*)d_in[9];
    const float* me_b1 = (const float*)d_in[10];
    const float* me_w2 = (const float*)d_in[11];
    const float* me_b2 = (const float*)d_in[12];
    const float* W_ih  = (const float*)d_in[13];
    const float* b_ih  = (const float*)d_in[14];
    const float* W_hh  = (const float*)d_in[15];
    const float* W_dt  = (const float*)d_in[16];
    const float* a_w0  = (const float*)d_in[17];
    const float* a_b0  = (const float*)d_in[18];
    const float* a_w1  = (const float*)d_in[19];
    const float* a_b1  = (const float*)d_in[20];
    const float* c_w0  = (const float*)d_in[21];
    const float* c_b0  = (const float*)d_in[22];
    const float* c_w1  = (const float*)d_in[23];
    const float* c_b1  = (const float*)d_in[24];
    const float* lstd  = (const float*)d_in[25];
    float* out = (float*)d_out;

    float* ws = (float*)d_ws;
    size_t off = 0;
    float* xw4  = ws + off; off += (size_t)16384*1024;
    float* hout = ws + off; off += (size_t)Bn*LH;
    float* cb   = ws + off; off += (size_t)Bn*LH;
    float* rl   = ws + off; off += (size_t)Bn*NR*HD;
    float* dtv  = ws + off; off += (size_t)16384;
    unsigned int* flags = (unsigned int*)(ws + off); off += 2048;

    u16* us = (u16*)(ws + off);
    size_t uo = 0;
    u16* li_bf = us + uo; uo += (size_t)16384*LIN;
    u16* pw0   = us + uo; uo += 128*32;
    u16* pw1   = us + uo; uo += 128*128;
    u16* pw2   = us + uo; uo += 128*128;
    u16* pm0   = us + uo; uo += 128*64;
    u16* pm1   = us + uo; uo += 128*128;
    u16* pm2   = us + uo; uo += 128*128;
    u16* pwih  = us + uo; uo += (size_t)1024*384;
    u16* pwhh  = us + uo; uo += (size_t)1024*256;
    u16* hb0   = us + uo; uo += (size_t)Bn*LH;
    u16* hb1   = us + uo; uo += (size_t)Bn*LH;

    k_setup<<<2936, 256, 0, stream>>>(re_w0, pw0, re_w1, pw1, re_w2, pw2,
                                      me_w0, pm0, me_w1, pm1, me_w2, pm2,
                                      W_ih, pwih, W_hh, pwhh, obs, dtv, flags);

    k_embed_market<<<4608, 256, 0, stream>>>(obs,
                                      pw0, re_b0, pw1, re_b1, pw2, re_b2,
                                      pm0, me_b0, pm1, me_b1, pm2, me_b2,
                                      li_bf, rl);

    k_xw<<<128, 256, 0, stream>>>(li_bf, pwih, b_ih, xw4);

    k_lstm_pair<<<32, 256, 0, stream>>>(xw4, pwhh, W_dt, dtv, hb0, hb1,
                                        hout, cb, flags);

    k_heads<<<256, 256, 0, stream>>>(hout, cb, rl,
        a_w0, a_b0, a_w1, a_b1, c_w0, c_b0, c_w1, c_b1, lstd, out);
}

// Round 16
// 448.524 us; speedup vs baseline: 1.0359x; 1.0359x over previous
//
#include <hip/hip_runtime.h>
#include <hip/hip_bf16.h>
#include <math.h>

#define Bn 256
#define Tn 64
#define OBSD 1000
#define NR 30
#define HD 128
#define LH 256
#define LIN 384
#define TDI 26

#define AM_OFF 0
#define ALS_OFF 15360
#define V_OFF 30720
#define H_OFF 30976
#define C_OFF 96512

typedef unsigned short u16;
typedef short bf16x8 __attribute__((ext_vector_type(8)));
typedef float f32x4 __attribute__((ext_vector_type(4)));

__device__ __forceinline__ float sigm(float x){ return 1.f/(1.f+__expf(-x)); }
__device__ __forceinline__ float tanhfast(float x){
    float ax = fabsf(x);
    float e = __expf(2.f*ax);
    float t = 1.f - 2.f/(e+1.f);
    return copysignf(t, x);
}

__device__ __forceinline__ u16 f2b(float f){
    union { __hip_bfloat16 h; u16 u; } cv;
    cv.h = __float2bfloat16(f);
    return cv.u;
}

// system-coherent (L3) access helpers — proven r5 protocol
__device__ __forceinline__ bf16x8 ld_b128_sys(const u16* p){
    bf16x8 r;
    asm volatile("global_load_dwordx4 %0, %1, off sc0 sc1"
                 : "=v"(r) : "v"(p) : "memory");
    return r;
}
__device__ __forceinline__ void st_b16_sys(u16* p, unsigned v){
    asm volatile("global_store_short %0, %1, off sc0 sc1"
                 :: "v"(p), "v"(v) : "memory");
}

#define MFMA(a,b,c) __builtin_amdgcn_mfma_f32_16x16x32_bf16(a,b,c,0,0,0)

// ---------------- fused setup kernel (packs + dtv + flags) ----------------
__device__ __forceinline__ void pack_one(
    const float* __restrict__ src, u16* __restrict__ dst,
    int N, int K, int Kpad, int t)
{
    if (t >= N*Kpad) return;
    int j = t / Kpad, k = t - j*Kpad;
    float v = (k < K) ? src[j*K + k] : 0.f;
    int ntile = j>>4, jr = j&15, kc = k>>5, ko = k&31;
    int lane = ((ko>>3)<<4) | jr, elem = ko&7;
    int KC = Kpad>>5;
    dst[(size_t)(((ntile*KC + kc)*64) + lane)*8 + elem] = f2b(v);
}

__device__ __forceinline__ void pack_gi_one(
    const float* __restrict__ src, u16* __restrict__ dst, int K, int t)
{
    int KC = K >> 5;
    if (t >= 1024*K) return;
    int n = t / K, k = t - n*K;
    int nt = n>>4, jr = n&15;
    int jg = nt>>2, g = nt&3;
    float v = src[(size_t)(g*256 + jg*16 + jr)*K + k];
    int kc = k>>5, ko = k&31;
    int lane = ((ko>>3)<<4) | jr, e = ko&7;
    dst[(size_t)(((nt*KC + kc)*64) + lane)*8 + e] = f2b(v);
}

__global__ __launch_bounds__(256) void k_setup(
    const float* __restrict__ re_w0, u16* __restrict__ pw0,
    const float* __restrict__ re_w1, u16* __restrict__ pw1,
    const float* __restrict__ re_w2, u16* __restrict__ pw2,
    const float* __restrict__ me_w0, u16* __restrict__ pm0,
    const float* __restrict__ me_w1, u16* __restrict__ pm1,
    const float* __restrict__ me_w2, u16* __restrict__ pm2,
    const float* __restrict__ W_ih,  u16* __restrict__ pwih,
    const float* __restrict__ W_hh,  u16* __restrict__ pwhh,
    const float* __restrict__ obs,   float* __restrict__ dtv,
    unsigned int* __restrict__ flags)
{
    int blk = blockIdx.x, tid = threadIdx.x;
    if (blk < 16){            pack_one(re_w0, pw0, 128, 32, 32,  blk*256 + tid); }
    else if (blk < 80){       pack_one(re_w1, pw1, 128,128,128, (blk-16)*256 + tid); }
    else if (blk < 144){      pack_one(re_w2, pw2, 128,128,128, (blk-80)*256 + tid); }
    else if (blk < 176){      pack_one(me_w0, pm0, 128, 40, 64, (blk-144)*256 + tid); }
    else if (blk < 240){      pack_one(me_w1, pm1, 128,128,128, (blk-176)*256 + tid); }
    else if (blk < 304){      pack_one(me_w2, pm2, 128,128,128, (blk-240)*256 + tid); }
    else if (blk < 1840){     pack_gi_one(W_ih, pwih, 384, (blk-304)*256 + tid); }
    else if (blk < 2864){     pack_gi_one(W_hh, pwhh, 256, (blk-1840)*256 + tid); }
    else if (blk < 2928){
        int idx = (blk-2864)*256 + tid;      // 16384
        int b = idx >> 6, t = idx & 63;
        dtv[t*256 + b] = obs[(size_t)idx*OBSD + TDI];
    } else {
        flags[(blk-2928)*256 + tid] = 0u;    // 2048 entries
    }
}

// ---------------- fused embed (2 bt/block, M=64) + market (32 rows/block) ----------------
// blocks [0,8192): runner embed; [8192,8704): market embed
__global__ __launch_bounds__(256) void k_embed_market(
    const float* __restrict__ obs,
    const u16* __restrict__ pw0, const float* __restrict__ re_b0,
    const u16* __restrict__ pw1, const float* __restrict__ re_b1,
    const u16* __restrict__ pw2, const float* __restrict__ re_b2,
    const u16* __restrict__ pm0, const float* __restrict__ me_b0,
    const u16* __restrict__ pm1, const float* __restrict__ me_b1,
    const u16* __restrict__ pm2, const float* __restrict__ me_b2,
    u16* __restrict__ li_bf, float* __restrict__ runner_last)
{
    __shared__ __align__(16) u16 smem[19968];   // union: embed 19968 u16, market 11008 u16
    __shared__ float bsf[384];

    int blk = blockIdx.x, tid = threadIdx.x;
    int lane = tid & 63, wv = tid >> 6;
    int lr = lane & 15, lk = lane >> 4;
    f32x4 zero = {0.f,0.f,0.f,0.f};

    if (blk < 8192){
        // ================= runner embed =================
        u16* xr   = smem;            // 64*40
        u16* act1 = smem + 2560;     // 64*136
        u16* act2 = smem + 11264;    // 64*136
        float* bs0 = bsf, *bs1 = bsf+128, *bs2 = bsf+256;

        int bt0 = blk*2;

        for (int idx=tid; idx<2048; idx+=256){
            int r = idx>>5, k = idx&31;
            int sb = r>>5, rr = r&31;
            const float* row = obs + (size_t)(bt0+sb)*OBSD;
            float v = 0.f;
            if (rr < 30) v = (k<24) ? row[30 + rr*24 + k] : row[760 + rr*8 + (k-24)];
            xr[r*40 + k] = f2b(v);
        }
        if (tid < 128){ bs0[tid]=re_b0[tid]; bs1[tid]=re_b1[tid]; bs2[tid]=re_b2[tid]; }
        __syncthreads();

        f32x4 d[4][2];

        // ---- layer 0 (K=32) ----
        {
            bf16x8 a0[4];
            #pragma unroll
            for (int m=0;m<4;m++) a0[m] = *(const bf16x8*)(xr + (m*16+lr)*40 + lk*8);
            #pragma unroll
            for (int ns=0; ns<2; ns++){
                int n = 2*wv + ns;
                bf16x8 b = *(const bf16x8*)(pw0 + (size_t)(n*64 + lane)*8);
                #pragma unroll
                for (int m=0;m<4;m++) d[m][ns] = MFMA(a0[m], b, zero);
            }
        }
        #pragma unroll
        for (int m=0;m<4;m++)
            #pragma unroll
            for (int ns=0;ns<2;ns++){
                int col = (2*wv+ns)*16 + lr;
                float bias = bs0[col];
                #pragma unroll
                for (int r=0;r<4;r++)
                    act1[(m*16+lk*4+r)*136 + col] = f2b(fmaxf(d[m][ns][r] + bias, 0.f));
            }
        __syncthreads();

        // ---- layer 1 (K=128) ----
        #pragma unroll
        for (int m=0;m<4;m++)
            #pragma unroll
            for (int ns=0;ns<2;ns++) d[m][ns] = zero;
        #pragma unroll
        for (int kc=0; kc<4; kc++){
            bf16x8 am[4];
            #pragma unroll
            for (int m=0;m<4;m++) am[m] = *(const bf16x8*)(act1 + (m*16+lr)*136 + kc*32 + lk*8);
            #pragma unroll
            for (int ns=0; ns<2; ns++){
                int n = 2*wv + ns;
                bf16x8 b = *(const bf16x8*)(pw1 + (size_t)((n*4 + kc)*64 + lane)*8);
                #pragma unroll
                for (int m=0;m<4;m++) d[m][ns] = MFMA(am[m], b, d[m][ns]);
            }
        }
        #pragma unroll
        for (int m=0;m<4;m++)
            #pragma unroll
            for (int ns=0;ns<2;ns++){
                int col = (2*wv+ns)*16 + lr;
                float bias = bs1[col];
                #pragma unroll
                for (int r=0;r<4;r++)
                    act2[(m*16+lk*4+r)*136 + col] = f2b(fmaxf(d[m][ns][r] + bias, 0.f));
            }
        __syncthreads();

        // ---- layer 2 (K=128, no relu) + reductions ----
        #pragma unroll
        for (int m=0;m<4;m++)
            #pragma unroll
            for (int ns=0;ns<2;ns++) d[m][ns] = zero;
        #pragma unroll
        for (int kc=0; kc<4; kc++){
            bf16x8 am[4];
            #pragma unroll
            for (int m=0;m<4;m++) am[m] = *(const bf16x8*)(act2 + (m*16+lr)*136 + kc*32 + lk*8);
            #pragma unroll
            for (int ns=0; ns<2; ns++){
                int n = 2*wv + ns;
                bf16x8 b = *(const bf16x8*)(pw2 + (size_t)((n*4 + kc)*64 + lane)*8);
                #pragma unroll
                for (int m=0;m<4;m++) d[m][ns] = MFMA(am[m], b, d[m][ns]);
            }
        }

        u16* li0 = li_bf + (size_t)bt0*LIN;
        u16* li1 = li_bf + (size_t)(bt0+1)*LIN;
        bool last1 = (((bt0+1) & 63) == 63);
        int bb1 = (bt0+1) >> 6;

        #pragma unroll
        for (int ns=0; ns<2; ns++){
            int col = (2*wv+ns)*16 + lr;
            float bias = bs2[col];
            float vals[4][4];
            float s0=0.f, m0=-3.4e38f, s1=0.f, m1=-3.4e38f;
            #pragma unroll
            for (int m=0;m<4;m++)
                #pragma unroll
                for (int r=0;r<4;r++){
                    int rw = m*16 + lk*4 + r;
                    float v = d[m][ns][r] + bias;
                    vals[m][r] = v;
                    if (m < 2){
                        bool ok = rw < 30;
                        s0 += ok ? v : 0.f;
                        m0 = fmaxf(m0, ok ? v : -3.4e38f);
                    } else {
                        bool ok = (rw-32) < 30;
                        s1 += ok ? v : 0.f;
                        m1 = fmaxf(m1, ok ? v : -3.4e38f);
                    }
                }
            s0 += __shfl_xor(s0, 16); s0 += __shfl_xor(s0, 32);
            m0 = fmaxf(m0, __shfl_xor(m0, 16)); m0 = fmaxf(m0, __shfl_xor(m0, 32));
            s1 += __shfl_xor(s1, 16); s1 += __shfl_xor(s1, 32);
            m1 = fmaxf(m1, __shfl_xor(m1, 16)); m1 = fmaxf(m1, __shfl_xor(m1, 32));
            if (lk == 0){
                li0[128 + col] = f2b(s0 * (1.0f/30.0f));
                li0[256 + col] = f2b(m0);
            }
            if (lk == 1){
                li1[128 + col] = f2b(s1 * (1.0f/30.0f));
                li1[256 + col] = f2b(m1);
            }
            if (last1){
                #pragma unroll
                for (int m=2;m<4;m++)
                    #pragma unroll
                    for (int r=0;r<4;r++){
                        int rw = m*16 + lk*4 + r - 32;
                        if (rw < 30) runner_last[(size_t)bb1*3840 + rw*128 + col] = vals[m][r];
                    }
            }
        }
    } else {
        // ================= market embed =================
        u16* xm  = smem;            // 32*72
        u16* ma1 = smem + 2304;     // 32*136
        u16* ma2 = smem + 6656;     // 32*136
        float* bs0 = bsf, *bs1 = bsf+128, *bs2 = bsf+256;

        int bt0 = (blk - 8192)*32;
        for (int idx=tid; idx<2048; idx+=256){
            int r = idx>>6, k = idx&63;
            const float* row = obs + (size_t)(bt0+r)*OBSD;
            float v = 0.f;
            if (k < 30) v = row[k];
            else if (k < 40) v = row[720 + k];
            xm[r*72 + k] = f2b(v);
        }
        if (tid < 128){ bs0[tid]=me_b0[tid]; bs1[tid]=me_b1[tid]; bs2[tid]=me_b2[tid]; }
        __syncthreads();

        f32x4 d[2][2];

        #pragma unroll
        for (int m=0;m<2;m++)
            #pragma unroll
            for (int ns=0;ns<2;ns++) d[m][ns] = zero;
        #pragma unroll
        for (int kc=0; kc<2; kc++){
            bf16x8 a0 = *(const bf16x8*)(xm + lr*72      + kc*32 + lk*8);
            bf16x8 a1 = *(const bf16x8*)(xm + (16+lr)*72 + kc*32 + lk*8);
            #pragma unroll
            for (int ns=0; ns<2; ns++){
                int n = 2*wv + ns;
                bf16x8 b = *(const bf16x8*)(pm0 + (size_t)((n*2 + kc)*64 + lane)*8);
                d[0][ns] = MFMA(a0, b, d[0][ns]);
                d[1][ns] = MFMA(a1, b, d[1][ns]);
            }
        }
        #pragma unroll
        for (int m=0;m<2;m++)
            #pragma unroll
            for (int ns=0;ns<2;ns++){
                int col = (2*wv+ns)*16 + lr;
                float bias = bs0[col];
                #pragma unroll
                for (int r=0;r<4;r++){
                    int rw = m*16 + lk*4 + r;
                    ma1[rw*136 + col] = f2b(fmaxf(d[m][ns][r] + bias, 0.f));
                }
            }
        __syncthreads();

        #pragma unroll
        for (int m=0;m<2;m++)
            #pragma unroll
            for (int ns=0;ns<2;ns++) d[m][ns] = zero;
        #pragma unroll
        for (int kc=0; kc<4; kc++){
            bf16x8 a0 = *(const bf16x8*)(ma1 + lr*136      + kc*32 + lk*8);
            bf16x8 a1 = *(const bf16x8*)(ma1 + (16+lr)*136 + kc*32 + lk*8);
            #pragma unroll
            for (int ns=0; ns<2; ns++){
                int n = 2*wv + ns;
                bf16x8 b = *(const bf16x8*)(pm1 + (size_t)((n*4 + kc)*64 + lane)*8);
                d[0][ns] = MFMA(a0, b, d[0][ns]);
                d[1][ns] = MFMA(a1, b, d[1][ns]);
            }
        }
        #pragma unroll
        for (int m=0;m<2;m++)
            #pragma unroll
            for (int ns=0;ns<2;ns++){
                int col = (2*wv+ns)*16 + lr;
                float bias = bs1[col];
                #pragma unroll
                for (int r=0;r<4;r++){
                    int rw = m*16 + lk*4 + r;
                    ma2[rw*136 + col] = f2b(fmaxf(d[m][ns][r] + bias, 0.f));
                }
            }
        __syncthreads();

        #pragma unroll
        for (int m=0;m<2;m++)
            #pragma unroll
            for (int ns=0;ns<2;ns++) d[m][ns] = zero;
        #pragma unroll
        for (int kc=0; kc<4; kc++){
            bf16x8 a0 = *(const bf16x8*)(ma2 + lr*136      + kc*32 + lk*8);
            bf16x8 a1 = *(const bf16x8*)(ma2 + (16+lr)*136 + kc*32 + lk*8);
            #pragma unroll
            for (int ns=0; ns<2; ns++){
                int n = 2*wv + ns;
                bf16x8 b = *(const bf16x8*)(pm2 + (size_t)((n*4 + kc)*64 + lane)*8);
                d[0][ns] = MFMA(a0, b, d[0][ns]);
                d[1][ns] = MFMA(a1, b, d[1][ns]);
            }
        }
        #pragma unroll
        for (int m=0;m<2;m++)
            #pragma unroll
            for (int ns=0;ns<2;ns++){
                int col = (2*wv+ns)*16 + lr;
                float bias = bs2[col];
                #pragma unroll
                for (int r=0;r<4;r++){
                    int rw = m*16 + lk*4 + r;
                    li_bf[(size_t)(bt0+rw)*LIN + col] = f2b(d[m][ns][r] + bias);
                }
            }
    }
}

// ---------------- xW precompute (MFMA), LDS-shared B panel ----------------
// Output layout: xw[(t*256 + b)*256 + jg*16+lr] as float4 {g0,g1,g2,g3}
__global__ __launch_bounds__(256) void k_xw(
    const u16* __restrict__ A, const u16* __restrict__ pwih,
    const float* __restrict__ b_ih, float* __restrict__ xw)
{
    __shared__ __align__(16) u16 bsh[48*512];   // 48 KB

    int tid = threadIdx.x;
    int lane = tid & 63, wv = tid >> 6;
    int lr = lane & 15, lk = lane >> 4;
    int r0 = blockIdx.x*128 + wv*32;

    bf16x8 a[2][12];
    #pragma unroll
    for (int m=0;m<2;m++)
        #pragma unroll
        for (int kc=0;kc<12;kc++)
            a[m][kc] = *(const bf16x8*)(A + (size_t)(r0+m*16+lr)*384 + kc*32 + lk*8);

    for (int jg=0; jg<16; jg++){
        {
            const bf16x8* src = (const bf16x8*)(pwih + (size_t)jg*48*512);
            bf16x8* dst = (bf16x8*)bsh;
            #pragma unroll
            for (int i=0;i<12;i++)
                dst[tid + i*256] = src[tid + i*256];
        }
        __syncthreads();

        f32x4 acc[2][4];
        #pragma unroll
        for (int g=0; g<4; g++){
            float bias = b_ih[g*256 + jg*16 + lr];
            f32x4 v = {bias,bias,bias,bias};
            acc[0][g]=v; acc[1][g]=v;
        }
        #pragma unroll
        for (int kc=0; kc<12; kc++){
            bf16x8 b0 = *(const bf16x8*)(bsh + (size_t)((0*12+kc)*64+lane)*8);
            bf16x8 b1 = *(const bf16x8*)(bsh + (size_t)((1*12+kc)*64+lane)*8);
            bf16x8 b2 = *(const bf16x8*)(bsh + (size_t)((2*12+kc)*64+lane)*8);
            bf16x8 b3 = *(const bf16x8*)(bsh + (size_t)((3*12+kc)*64+lane)*8);
            #pragma unroll
            for (int m=0;m<2;m++){
                acc[m][0] = MFMA(a[m][kc], b0, acc[m][0]);
                acc[m][1] = MFMA(a[m][kc], b1, acc[m][1]);
                acc[m][2] = MFMA(a[m][kc], b2, acc[m][2]);
                acc[m][3] = MFMA(a[m][kc], b3, acc[m][3]);
            }
        }
        #pragma unroll
        for (int m=0;m<2;m++)
            #pragma unroll
            for (int r=0;r<4;r++){
                int row = r0 + m*16 + lk*4 + r;       // bt index (b*64+t)
                int trow = (row & 63)*256 + (row >> 6);
                float4 pk;
                pk.x = acc[m][0][r]; pk.y = acc[m][1][r];
                pk.z = acc[m][2][r]; pk.w = acc[m][3][r];
                *(float4*)(xw + ((size_t)trow*256 + jg*16 + lr)*4) = pk;
            }
        __syncthreads();
    }
}

// ---------------- pairwise persistent LSTM (r11-green protocol; acc-init hoisted) ----------------
__global__ __launch_bounds__(256,1) void k_lstm_pair(
    const float* __restrict__ xw, const u16* __restrict__ pwhh,
    const float* __restrict__ W_dt, const float* __restrict__ dtv,
    u16* __restrict__ hb0, u16* __restrict__ hb1,
    float* __restrict__ hout, float* __restrict__ cout,
    unsigned int* __restrict__ flags)
{
    int tid = threadIdx.x;
    int lane = tid & 63, wv = tid >> 6;
    int lr = lane & 15, lk = lane >> 4;
    int blk = blockIdx.x;
    int p = blk >> 1, hf = blk & 1;
    int bb0 = p*16;
    int jg0 = hf*8 + wv*2;

    bf16x8 bfr[2][4][8];
    #pragma unroll
    for (int jl=0;jl<2;jl++)
        #pragma unroll
        for (int g=0;g<4;g++)
            #pragma unroll
            for (int kc=0;kc<8;kc++)
                bfr[jl][g][kc] = *(const bf16x8*)(pwhh + (size_t)((((jg0+jl)*4+g)*8+kc)*64+lane)*8);

    float wdt0 = W_dt[jg0*16 + lr];
    float wdt1 = W_dt[(jg0+1)*16 + lr];

    float cst[2][4] = {{0.f,0.f,0.f,0.f},{0.f,0.f,0.f,0.f}};
    bf16x8 a[8];
    #pragma unroll
    for (int kc=0;kc<8;kc++) a[kc] = (bf16x8)(short)0;

    int bth = bb0 + lk*4;

    float4 xwn[2][4];
    #pragma unroll
    for (int jl=0;jl<2;jl++)
        #pragma unroll
        for (int r=0;r<4;r++)
            xwn[jl][r] = *(const float4*)(xw + ((size_t)(bth+r)*256 + (jg0+jl)*16 + lr)*4);
    float4 dtn = *(const float4*)(dtv + bth);

    // acc for t=0 (built from xwn in prologue)
    f32x4 acc[2][4];
    #pragma unroll
    for (int jl=0;jl<2;jl++){
        f32x4 v0, v1, v2, v3;
        #pragma unroll
        for (int r=0;r<4;r++){
            v0[r] = xwn[jl][r].x; v1[r] = xwn[jl][r].y;
            v2[r] = xwn[jl][r].z; v3[r] = xwn[jl][r].w;
        }
        acc[jl][0] = v0; acc[jl][1] = v1; acc[jl][2] = v2; acc[jl][3] = v3;
    }

    unsigned int* myflag   = &flags[blk*64];
    unsigned int* partflag = &flags[(blk^1)*64];

    for (int t=0; t<64; t++){
        // a[] (inline-asm loads) must be complete before MFMA
        asm volatile("s_waitcnt vmcnt(0)" ::: "memory");
        __builtin_amdgcn_sched_barrier(0);

        #pragma unroll
        for (int kc=0; kc<8; kc++){
            #pragma unroll
            for (int jl=0;jl<2;jl++){
                acc[jl][0] = MFMA(a[kc], bfr[jl][0][kc], acc[jl][0]);
                acc[jl][1] = MFMA(a[kc], bfr[jl][1][kc], acc[jl][1]);
                acc[jl][2] = MFMA(a[kc], bfr[jl][2][kc], acc[jl][2]);
                acc[jl][3] = MFMA(a[kc], bfr[jl][3][kc], acc[jl][3]);
            }
        }

        u16* hw = (t&1) ? hb1 : hb0;
        #pragma unroll
        for (int jl=0;jl<2;jl++){
            float wdt = jl ? wdt1 : wdt0;
            int jcol = (jg0+jl)*16 + lr;
            #pragma unroll
            for (int r=0;r<4;r++){
                float dd = (r==0)?dtn.x:(r==1)?dtn.y:(r==2)?dtn.z:dtn.w;
                float gi = sigm(acc[jl][0][r]);
                float gf = sigm(acc[jl][1][r] + wdt*dd);
                float gg = tanhfast(acc[jl][2][r]);
                float go = sigm(acc[jl][3][r]);
                float cn = fmaf(gf, cst[jl][r], gi*gg);
                cst[jl][r] = cn;
                float hv = go * tanhfast(cn);
                if (t < 63){
                    st_b16_sys(hw + (size_t)(bth+r)*256 + jcol, (unsigned)f2b(hv));
                } else {
                    hout[(size_t)(bth+r)*256 + jcol] = hv;
                    cout[(size_t)(bth+r)*256 + jcol] = cn;
                }
            }
        }

        if (t < 63){
            // own h slice visible at L3 before flag
            asm volatile("s_waitcnt vmcnt(0)" ::: "memory");
            __syncthreads();
            if (tid == 0)
                __hip_atomic_store(myflag, (unsigned)(t+1),
                                   __ATOMIC_RELAXED, __HIP_MEMORY_SCOPE_SYSTEM);

            // prefetch next xw/dt (plain cached loads; overlap the poll)
            #pragma unroll
            for (int jl=0;jl<2;jl++)
                #pragma unroll
                for (int r=0;r<4;r++)
                    xwn[jl][r] = *(const float4*)(xw + ((size_t)((t+1)*256 + bth+r)*256 + (jg0+jl)*16 + lr)*4);
            dtn = *(const float4*)(dtv + (t+1)*256 + bth);

            if (lane == 0){
                while (__hip_atomic_load(partflag, __ATOMIC_RELAXED,
                                         __HIP_MEMORY_SCOPE_SYSTEM) < (unsigned)(t+1)) {}
            }
            __builtin_amdgcn_wave_barrier();

            const u16* hr = (t&1) ? hb1 : hb0;
            #pragma unroll
            for (int kc=0; kc<8; kc++)
                a[kc] = ld_b128_sys(hr + (size_t)(bb0+lr)*256 + kc*32 + lk*8);

            // build acc for t+1 in the h-load shadow (xwn complete: poll's
            // value-use drained all older loads)
            #pragma unroll
            for (int jl=0;jl<2;jl++){
                f32x4 v0, v1, v2, v3;
                #pragma unroll
                for (int r=0;r<4;r++){
                    v0[r] = xwn[jl][r].x; v1[r] = xwn[jl][r].y;
                    v2[r] = xwn[jl][r].z; v3[r] = xwn[jl][r].w;
                }
                acc[jl][0] = v0; acc[jl][1] = v1; acc[jl][2] = v2; acc[jl][3] = v3;
            }
        }
    }
}

// ---------------- heads (fp32) ----------------
__device__ __forceinline__ void dense30(
    const float* in, int istride,
    const float* __restrict__ W, int wstride, int K,
    const float* __restrict__ bias, const float* extra,
    float* outp, int ostride, bool relu, int j, int rh)
{
    float acc[15];
    #pragma unroll
    for (int i=0;i<15;i++) acc[i]=0.f;
    const float* w = W + j*wstride;
    for (int k=0;k<K;k+=4){
        float4 wv = *(const float4*)(w+k);
        #pragma unroll
        for (int i=0;i<15;i++){
            float4 xv = *(const float4*)(in + (rh+2*i)*istride + k);
            acc[i] = fmaf(wv.x,xv.x,acc[i]);
            acc[i] = fmaf(wv.y,xv.y,acc[i]);
            acc[i] = fmaf(wv.z,xv.z,acc[i]);
            acc[i] = fmaf(wv.w,xv.w,acc[i]);
        }
    }
    float bb = bias[j] + (extra ? extra[j] : 0.f);
    #pragma unroll
    for (int i=0;i<15;i++){
        float v = acc[i]+bb;
        outp[(rh+2*i)*ostride+j] = relu ? fmaxf(v,0.f) : v;
    }
}

__device__ __forceinline__ float dense1(
    const float* in, const float* __restrict__ W,
    const float* __restrict__ bias, int K, int j)
{
    const float* w = W + j*K;
    float s = 0.f;
    for (int k=0;k<K;k+=4){
        float4 wv = *(const float4*)(w+k);
        float4 xv = *(const float4*)(in+k);
        s = fmaf(wv.x,xv.x,s); s = fmaf(wv.y,xv.y,s);
        s = fmaf(wv.z,xv.z,s); s = fmaf(wv.w,xv.w,s);
    }
    return s + bias[j];
}

__global__ __launch_bounds__(256) void k_heads(
    const float* __restrict__ h, const float* __restrict__ cbuf,
    const float* __restrict__ rl,
    const float* __restrict__ a_w0, const float* __restrict__ a_b0,
    const float* __restrict__ a_w1, const float* __restrict__ a_b1,
    const float* __restrict__ c_w0, const float* __restrict__ c_b0,
    const float* __restrict__ c_w1, const float* __restrict__ c_b1,
    const float* __restrict__ log_std,
    float* __restrict__ out)
{
    __shared__ __align__(16) float hv[LH];
    __shared__ __align__(16) float rls[NR][HD];
    __shared__ __align__(16) float hid[NR][HD];
    __shared__ __align__(16) float dot2[HD];
    __shared__ __align__(16) float red[128];

    int b = blockIdx.x, tid = threadIdx.x;
    hv[tid] = h[b*LH + tid];
    for (int idx=tid; idx<NR*HD; idx+=256) rls[idx>>7][idx&127] = rl[(size_t)b*NR*HD + idx];
    __syncthreads();

    if (tid < 128){
        const float* w = a_w0 + tid*LIN + HD;
        float s = 0.f;
        for (int k=0;k<LH;k+=4){
            float4 wv = *(const float4*)(w+k);
            s = fmaf(wv.x,hv[k],s); s = fmaf(wv.y,hv[k+1],s);
            s = fmaf(wv.z,hv[k+2],s); s = fmaf(wv.w,hv[k+3],s);
        }
        dot2[tid] = s;
    }
    __syncthreads();

    int j = tid & 127, rh = tid >> 7;
    dense30(&rls[0][0], HD, a_w0, LIN, HD, a_b0, dot2, &hid[0][0], HD, true, j, rh);
    __syncthreads();

    if (tid < 60){
        int r = tid >> 1, o = tid & 1;
        const float* w = a_w1 + o*HD;
        float s = a_b1[o];
        for (int k=0;k<HD;k++) s = fmaf(hid[r][k], w[k], s);
        out[AM_OFF + b*60 + tid] = s;
        out[ALS_OFF + b*60 + tid] = log_std[tid];
    }

    float term = 0.f;
    if (tid < 128) term = fmaxf(dense1(hv, c_w0, c_b0, LH, tid), 0.f) * c_w1[tid];
    if (tid < 128) red[tid] = term;
    __syncthreads();
    for (int s2=64; s2>0; s2>>=1){
        if (tid < s2) red[tid] += red[tid+s2];
        __syncthreads();
    }
    if (tid == 0) out[V_OFF + b] = red[0] + c_b1[0];

    out[H_OFF + b*LH + tid] = hv[tid];
    out[C_OFF + b*LH + tid] = cbuf[b*LH + tid];
}

extern "C" void kernel_launch(void* const* d_in, const int* in_sizes, int n_in,
                              void* d_out, int out_size, void* d_ws, size_t ws_size,
                              hipStream_t stream)
{
    const float* obs   = (const float*)d_in[0];
    const float* re_w0 = (const float*)d_in[1];
    const float* re_b0 = (const float*)d_in[2];
    const float* re_w1 = (const float*)d_in[3];
    const float* re_b1 = (const float*)d_in[4];
    const float* re_w2 = (const float*)d_in[5];
    const float* re_b2 = (const float*)d_in[6];
    const float* me_w0 = (const float*)d_in[7];
    const float* me_b0 = (const float*)d_in[8];
    const float* me_w1 = (const float*)d_in[9];
    const float* me_b1 = (const float*)d_in[10];
    const float* me_w2 = (const float*)d_in[11];
    const float* me_b2 = (const float*)d_in[12];
    const float* W_ih  = (const float*)d_in[13];
    const float* b_ih  = (const float*)d_in[14];
    const float* W_hh  = (const float*)d_in[15];
    const float* W_dt  = (const float*)d_in[16];
    const float* a_w0  = (const float*)d_in[17];
    const float* a_b0  = (const float*)d_in[18];
    const float* a_w1  = (const float*)d_in[19];
    const float* a_b1  = (const float*)d_in[20];
    const float* c_w0  = (const float*)d_in[21];
    const float* c_b0  = (const float*)d_in[22];
    const float* c_w1  = (const float*)d_in[23];
    const float* c_b1  = (const float*)d_in[24];
    const float* lstd  = (const float*)d_in[25];
    float* out = (float*)d_out;

    float* ws = (float*)d_ws;
    size_t off = 0;
    float* xw4  = ws + off; off += (size_t)16384*1024;
    float* hout = ws + off; off += (size_t)Bn*LH;
    float* cb   = ws + off; off += (size_t)Bn*LH;
    float* rl   = ws + off; off += (size_t)Bn*NR*HD;
    float* dtv  = ws + off; off += (size_t)16384;
    unsigned int* flags = (unsigned int*)(ws + off); off += 2048;

    u16* us = (u16*)(ws + off);
    size_t uo = 0;
    u16* li_bf = us + uo; uo += (size_t)16384*LIN;
    u16* pw0   = us + uo; uo += 128*32;
    u16* pw1   = us + uo; uo += 128*128;
    u16* pw2   = us + uo; uo += 128*128;
    u16* pm0   = us + uo; uo += 128*64;
    u16* pm1   = us + uo; uo += 128*128;
    u16* pm2   = us + uo; uo += 128*128;
    u16* pwih  = us + uo; uo += (size_t)1024*384;
    u16* pwhh  = us + uo; uo += (size_t)1024*256;
    u16* hb0   = us + uo; uo += (size_t)Bn*LH;
    u16* hb1   = us + uo; uo += (size_t)Bn*LH;

    k_setup<<<2936, 256, 0, stream>>>(re_w0, pw0, re_w1, pw1, re_w2, pw2,
                                      me_w0, pm0, me_w1, pm1, me_w2, pm2,
                                      W_ih, pwih, W_hh, pwhh, obs, dtv, flags);

    k_embed_market<<<8704, 256, 0, stream>>>(obs,
                                      pw0, re_b0, pw1, re_b1, pw2, re_b2,
                                      pm0, me_b0, pm1, me_b1, pm2, me_b2,
                                      li_bf, rl);

    k_xw<<<128, 256, 0, stream>>>(li_bf, pwih, b_ih, xw4);

    k_lstm_pair<<<32, 256, 0, stream>>>(xw4, pwhh, W_dt, dtv, hb0, hb1,
                                        hout, cb, flags);

    k_heads<<<256, 256, 0, stream>>>(hout, cb, rl,
        a_w0, a_b0, a_w1, a_b1, c_w0, c_b0, c_w1, c_b1, lstd, out);
}

// Round 17
// 440.615 us; speedup vs baseline: 1.0545x; 1.0179x over previous
//
#include <hip/hip_runtime.h>
#include <hip/hip_bf16.h>
#include <math.h>

#define Bn 256
#define Tn 64
#define OBSD 1000
#define NR 30
#define HD 128
#define LH 256
#define LIN 384
#define TDI 26

#define AM_OFF 0
#define ALS_OFF 15360
#define V_OFF 30720
#define H_OFF 30976
#define C_OFF 96512

typedef unsigned short u16;
typedef short bf16x8 __attribute__((ext_vector_type(8)));
typedef float f32x4 __attribute__((ext_vector_type(4)));

__device__ __forceinline__ float sigm(float x){ return 1.f/(1.f+__expf(-x)); }
__device__ __forceinline__ float tanhfast(float x){
    float ax = fabsf(x);
    float e = __expf(2.f*ax);
    float t = 1.f - 2.f/(e+1.f);
    return copysignf(t, x);
}

__device__ __forceinline__ u16 f2b(float f){
    union { __hip_bfloat16 h; u16 u; } cv;
    cv.h = __float2bfloat16(f);
    return cv.u;
}

// system-coherent (L3) access helpers — proven r5 protocol
__device__ __forceinline__ bf16x8 ld_b128_sys(const u16* p){
    bf16x8 r;
    asm volatile("global_load_dwordx4 %0, %1, off sc0 sc1"
                 : "=v"(r) : "v"(p) : "memory");
    return r;
}
__device__ __forceinline__ void st_b16_sys(u16* p, unsigned v){
    asm volatile("global_store_short %0, %1, off sc0 sc1"
                 :: "v"(p), "v"(v) : "memory");
}
__device__ __forceinline__ f32x4 ld_f32x4_sys(const float* p){
    f32x4 r;
    asm volatile("global_load_dwordx4 %0, %1, off sc0 sc1"
                 : "=v"(r) : "v"(p) : "memory");
    return r;
}
__device__ __forceinline__ void st_f32x4_sys(float* p, f32x4 v){
    asm volatile("global_store_dwordx4 %0, %1, off sc0 sc1"
                 :: "v"(p), "v"(v) : "memory");
}

#define MFMA(a,b,c) __builtin_amdgcn_mfma_f32_16x16x32_bf16(a,b,c,0,0,0)

// ---------------- fused setup kernel (packs + dtv + flags) ----------------
__device__ __forceinline__ void pack_one(
    const float* __restrict__ src, u16* __restrict__ dst,
    int N, int K, int Kpad, int t)
{
    if (t >= N*Kpad) return;
    int j = t / Kpad, k = t - j*Kpad;
    float v = (k < K) ? src[j*K + k] : 0.f;
    int ntile = j>>4, jr = j&15, kc = k>>5, ko = k&31;
    int lane = ((ko>>3)<<4) | jr, elem = ko&7;
    int KC = Kpad>>5;
    dst[(size_t)(((ntile*KC + kc)*64) + lane)*8 + elem] = f2b(v);
}

__device__ __forceinline__ void pack_gi_one(
    const float* __restrict__ src, u16* __restrict__ dst, int K, int t)
{
    int KC = K >> 5;
    if (t >= 1024*K) return;
    int n = t / K, k = t - n*K;
    int nt = n>>4, jr = n&15;
    int jg = nt>>2, g = nt&3;
    float v = src[(size_t)(g*256 + jg*16 + jr)*K + k];
    int kc = k>>5, ko = k&31;
    int lane = ((ko>>3)<<4) | jr, e = ko&7;
    dst[(size_t)(((nt*KC + kc)*64) + lane)*8 + e] = f2b(v);
}

__global__ __launch_bounds__(256) void k_setup(
    const float* __restrict__ re_w0, u16* __restrict__ pw0,
    const float* __restrict__ re_w1, u16* __restrict__ pw1,
    const float* __restrict__ re_w2, u16* __restrict__ pw2,
    const float* __restrict__ me_w0, u16* __restrict__ pm0,
    const float* __restrict__ me_w1, u16* __restrict__ pm1,
    const float* __restrict__ me_w2, u16* __restrict__ pm2,
    const float* __restrict__ W_ih,  u16* __restrict__ pwih,
    const float* __restrict__ W_hh,  u16* __restrict__ pwhh,
    const float* __restrict__ obs,   float* __restrict__ dtv,
    unsigned int* __restrict__ flags)
{
    int blk = blockIdx.x, tid = threadIdx.x;
    if (blk < 16){            pack_one(re_w0, pw0, 128, 32, 32,  blk*256 + tid); }
    else if (blk < 80){       pack_one(re_w1, pw1, 128,128,128, (blk-16)*256 + tid); }
    else if (blk < 144){      pack_one(re_w2, pw2, 128,128,128, (blk-80)*256 + tid); }
    else if (blk < 176){      pack_one(me_w0, pm0, 128, 40, 64, (blk-144)*256 + tid); }
    else if (blk < 240){      pack_one(me_w1, pm1, 128,128,128, (blk-176)*256 + tid); }
    else if (blk < 304){      pack_one(me_w2, pm2, 128,128,128, (blk-240)*256 + tid); }
    else if (blk < 1840){     pack_gi_one(W_ih, pwih, 384, (blk-304)*256 + tid); }
    else if (blk < 2864){     pack_gi_one(W_hh, pwhh, 256, (blk-1840)*256 + tid); }
    else if (blk < 2928){
        int idx = (blk-2864)*256 + tid;      // 16384
        int b = idx >> 6, t = idx & 63;
        dtv[t*256 + b] = obs[(size_t)idx*OBSD + TDI];
    } else {
        flags[(blk-2928)*256 + tid] = 0u;    // 2304 entries (9 blocks)
    }
}

// ---------------- fused embed (2 bt/block, M=64) + market (32 rows/block) ----------------
__global__ __launch_bounds__(256) void k_embed_market(
    const float* __restrict__ obs,
    const u16* __restrict__ pw0, const float* __restrict__ re_b0,
    const u16* __restrict__ pw1, const float* __restrict__ re_b1,
    const u16* __restrict__ pw2, const float* __restrict__ re_b2,
    const u16* __restrict__ pm0, const float* __restrict__ me_b0,
    const u16* __restrict__ pm1, const float* __restrict__ me_b1,
    const u16* __restrict__ pm2, const float* __restrict__ me_b2,
    u16* __restrict__ li_bf, float* __restrict__ runner_last)
{
    __shared__ __align__(16) u16 smem[19968];
    __shared__ float bsf[384];

    int blk = blockIdx.x, tid = threadIdx.x;
    int lane = tid & 63, wv = tid >> 6;
    int lr = lane & 15, lk = lane >> 4;
    f32x4 zero = {0.f,0.f,0.f,0.f};

    if (blk < 8192){
        u16* xr   = smem;
        u16* act1 = smem + 2560;
        u16* act2 = smem + 11264;
        float* bs0 = bsf, *bs1 = bsf+128, *bs2 = bsf+256;

        int bt0 = blk*2;

        for (int idx=tid; idx<2048; idx+=256){
            int r = idx>>5, k = idx&31;
            int sb = r>>5, rr = r&31;
            const float* row = obs + (size_t)(bt0+sb)*OBSD;
            float v = 0.f;
            if (rr < 30) v = (k<24) ? row[30 + rr*24 + k] : row[760 + rr*8 + (k-24)];
            xr[r*40 + k] = f2b(v);
        }
        if (tid < 128){ bs0[tid]=re_b0[tid]; bs1[tid]=re_b1[tid]; bs2[tid]=re_b2[tid]; }
        __syncthreads();

        f32x4 d[4][2];

        {
            bf16x8 a0[4];
            #pragma unroll
            for (int m=0;m<4;m++) a0[m] = *(const bf16x8*)(xr + (m*16+lr)*40 + lk*8);
            #pragma unroll
            for (int ns=0; ns<2; ns++){
                int n = 2*wv + ns;
                bf16x8 b = *(const bf16x8*)(pw0 + (size_t)(n*64 + lane)*8);
                #pragma unroll
                for (int m=0;m<4;m++) d[m][ns] = MFMA(a0[m], b, zero);
            }
        }
        #pragma unroll
        for (int m=0;m<4;m++)
            #pragma unroll
            for (int ns=0;ns<2;ns++){
                int col = (2*wv+ns)*16 + lr;
                float bias = bs0[col];
                #pragma unroll
                for (int r=0;r<4;r++)
                    act1[(m*16+lk*4+r)*136 + col] = f2b(fmaxf(d[m][ns][r] + bias, 0.f));
            }
        __syncthreads();

        #pragma unroll
        for (int m=0;m<4;m++)
            #pragma unroll
            for (int ns=0;ns<2;ns++) d[m][ns] = zero;
        #pragma unroll
        for (int kc=0; kc<4; kc++){
            bf16x8 am[4];
            #pragma unroll
            for (int m=0;m<4;m++) am[m] = *(const bf16x8*)(act1 + (m*16+lr)*136 + kc*32 + lk*8);
            #pragma unroll
            for (int ns=0; ns<2; ns++){
                int n = 2*wv + ns;
                bf16x8 b = *(const bf16x8*)(pw1 + (size_t)((n*4 + kc)*64 + lane)*8);
                #pragma unroll
                for (int m=0;m<4;m++) d[m][ns] = MFMA(am[m], b, d[m][ns]);
            }
        }
        #pragma unroll
        for (int m=0;m<4;m++)
            #pragma unroll
            for (int ns=0;ns<2;ns++){
                int col = (2*wv+ns)*16 + lr;
                float bias = bs1[col];
                #pragma unroll
                for (int r=0;r<4;r++)
                    act2[(m*16+lk*4+r)*136 + col] = f2b(fmaxf(d[m][ns][r] + bias, 0.f));
            }
        __syncthreads();

        #pragma unroll
        for (int m=0;m<4;m++)
            #pragma unroll
            for (int ns=0;ns<2;ns++) d[m][ns] = zero;
        #pragma unroll
        for (int kc=0; kc<4; kc++){
            bf16x8 am[4];
            #pragma unroll
            for (int m=0;m<4;m++) am[m] = *(const bf16x8*)(act2 + (m*16+lr)*136 + kc*32 + lk*8);
            #pragma unroll
            for (int ns=0; ns<2; ns++){
                int n = 2*wv + ns;
                bf16x8 b = *(const bf16x8*)(pw2 + (size_t)((n*4 + kc)*64 + lane)*8);
                #pragma unroll
                for (int m=0;m<4;m++) d[m][ns] = MFMA(am[m], b, d[m][ns]);
            }
        }

        u16* li0 = li_bf + (size_t)bt0*LIN;
        u16* li1 = li_bf + (size_t)(bt0+1)*LIN;
        bool last1 = (((bt0+1) & 63) == 63);
        int bb1 = (bt0+1) >> 6;

        #pragma unroll
        for (int ns=0; ns<2; ns++){
            int col = (2*wv+ns)*16 + lr;
            float bias = bs2[col];
            float vals[4][4];
            float s0=0.f, m0=-3.4e38f, s1=0.f, m1=-3.4e38f;
            #pragma unroll
            for (int m=0;m<4;m++)
                #pragma unroll
                for (int r=0;r<4;r++){
                    int rw = m*16 + lk*4 + r;
                    float v = d[m][ns][r] + bias;
                    vals[m][r] = v;
                    if (m < 2){
                        bool ok = rw < 30;
                        s0 += ok ? v : 0.f;
                        m0 = fmaxf(m0, ok ? v : -3.4e38f);
                    } else {
                        bool ok = (rw-32) < 30;
                        s1 += ok ? v : 0.f;
                        m1 = fmaxf(m1, ok ? v : -3.4e38f);
                    }
                }
            s0 += __shfl_xor(s0, 16); s0 += __shfl_xor(s0, 32);
            m0 = fmaxf(m0, __shfl_xor(m0, 16)); m0 = fmaxf(m0, __shfl_xor(m0, 32));
            s1 += __shfl_xor(s1, 16); s1 += __shfl_xor(s1, 32);
            m1 = fmaxf(m1, __shfl_xor(m1, 16)); m1 = fmaxf(m1, __shfl_xor(m1, 32));
            if (lk == 0){
                li0[128 + col] = f2b(s0 * (1.0f/30.0f));
                li0[256 + col] = f2b(m0);
            }
            if (lk == 1){
                li1[128 + col] = f2b(s1 * (1.0f/30.0f));
                li1[256 + col] = f2b(m1);
            }
            if (last1){
                #pragma unroll
                for (int m=2;m<4;m++)
                    #pragma unroll
                    for (int r=0;r<4;r++){
                        int rw = m*16 + lk*4 + r - 32;
                        if (rw < 30) runner_last[(size_t)bb1*3840 + rw*128 + col] = vals[m][r];
                    }
            }
        }
    } else {
        u16* xm  = smem;
        u16* ma1 = smem + 2304;
        u16* ma2 = smem + 6656;
        float* bs0 = bsf, *bs1 = bsf+128, *bs2 = bsf+256;

        int bt0 = (blk - 8192)*32;
        for (int idx=tid; idx<2048; idx+=256){
            int r = idx>>6, k = idx&63;
            const float* row = obs + (size_t)(bt0+r)*OBSD;
            float v = 0.f;
            if (k < 30) v = row[k];
            else if (k < 40) v = row[720 + k];
            xm[r*72 + k] = f2b(v);
        }
        if (tid < 128){ bs0[tid]=me_b0[tid]; bs1[tid]=me_b1[tid]; bs2[tid]=me_b2[tid]; }
        __syncthreads();

        f32x4 d[2][2];

        #pragma unroll
        for (int m=0;m<2;m++)
            #pragma unroll
            for (int ns=0;ns<2;ns++) d[m][ns] = zero;
        #pragma unroll
        for (int kc=0; kc<2; kc++){
            bf16x8 a0 = *(const bf16x8*)(xm + lr*72      + kc*32 + lk*8);
            bf16x8 a1 = *(const bf16x8*)(xm + (16+lr)*72 + kc*32 + lk*8);
            #pragma unroll
            for (int ns=0; ns<2; ns++){
                int n = 2*wv + ns;
                bf16x8 b = *(const bf16x8*)(pm0 + (size_t)((n*2 + kc)*64 + lane)*8);
                d[0][ns] = MFMA(a0, b, d[0][ns]);
                d[1][ns] = MFMA(a1, b, d[1][ns]);
            }
        }
        #pragma unroll
        for (int m=0;m<2;m++)
            #pragma unroll
            for (int ns=0;ns<2;ns++){
                int col = (2*wv+ns)*16 + lr;
                float bias = bs0[col];
                #pragma unroll
                for (int r=0;r<4;r++){
                    int rw = m*16 + lk*4 + r;
                    ma1[rw*136 + col] = f2b(fmaxf(d[m][ns][r] + bias, 0.f));
                }
            }
        __syncthreads();

        #pragma unroll
        for (int m=0;m<2;m++)
            #pragma unroll
            for (int ns=0;ns<2;ns++) d[m][ns] = zero;
        #pragma unroll
        for (int kc=0; kc<4; kc++){
            bf16x8 a0 = *(const bf16x8*)(ma1 + lr*136      + kc*32 + lk*8);
            bf16x8 a1 = *(const bf16x8*)(ma1 + (16+lr)*136 + kc*32 + lk*8);
            #pragma unroll
            for (int ns=0; ns<2; ns++){
                int n = 2*wv + ns;
                bf16x8 b = *(const bf16x8*)(pm1 + (size_t)((n*4 + kc)*64 + lane)*8);
                d[0][ns] = MFMA(a0, b, d[0][ns]);
                d[1][ns] = MFMA(a1, b, d[1][ns]);
            }
        }
        #pragma unroll
        for (int m=0;m<2;m++)
            #pragma unroll
            for (int ns=0;ns<2;ns++){
                int col = (2*wv+ns)*16 + lr;
                float bias = bs1[col];
                #pragma unroll
                for (int r=0;r<4;r++){
                    int rw = m*16 + lk*4 + r;
                    ma2[rw*136 + col] = f2b(fmaxf(d[m][ns][r] + bias, 0.f));
                }
            }
        __syncthreads();

        #pragma unroll
        for (int m=0;m<2;m++)
            #pragma unroll
            for (int ns=0;ns<2;ns++) d[m][ns] = zero;
        #pragma unroll
        for (int kc=0; kc<4; kc++){
            bf16x8 a0 = *(const bf16x8*)(ma2 + lr*136      + kc*32 + lk*8);
            bf16x8 a1 = *(const bf16x8*)(ma2 + (16+lr)*136 + kc*32 + lk*8);
            #pragma unroll
            for (int ns=0; ns<2; ns++){
                int n = 2*wv + ns;
                bf16x8 b = *(const bf16x8*)(pm2 + (size_t)((n*4 + kc)*64 + lane)*8);
                d[0][ns] = MFMA(a0, b, d[0][ns]);
                d[1][ns] = MFMA(a1, b, d[1][ns]);
            }
        }
        #pragma unroll
        for (int m=0;m<2;m++)
            #pragma unroll
            for (int ns=0;ns<2;ns++){
                int col = (2*wv+ns)*16 + lr;
                float bias = bs2[col];
                #pragma unroll
                for (int r=0;r<4;r++){
                    int rw = m*16 + lk*4 + r;
                    li_bf[(size_t)(bt0+rw)*LIN + col] = f2b(d[m][ns][r] + bias);
                }
            }
    }
}

// ---------------- fused xw(t-major producers) + LSTM consumers ----------------
// blocks 0..31: LSTM pairs (r16 protocol + xw-ready gating).
// blocks 32..159: xw producer for (t = (blk-32)>>1, half = (blk-32)&1):
//   128 batches of fixed t; sc0sc1 stores; ordered completion counter.
__global__ __launch_bounds__(256,1) void k_xwlstm(
    const u16* __restrict__ A, const u16* __restrict__ pwih,
    const float* __restrict__ b_ih, float* __restrict__ xw,
    const u16* __restrict__ pwhh, const float* __restrict__ W_dt,
    const float* __restrict__ dtv,
    u16* __restrict__ hb0, u16* __restrict__ hb1,
    float* __restrict__ hout, float* __restrict__ cout,
    unsigned int* __restrict__ flags)
{
    __shared__ __align__(16) u16 bsh[48*512];   // xw path only

    int blk = blockIdx.x;
    int tid = threadIdx.x;
    int lane = tid & 63, wv = tid >> 6;
    int lr = lane & 15, lk = lane >> 4;

    if (blk >= 32){
        // ================= xw producer =================
        int tb = blk - 32;
        int t = tb >> 1, half = tb & 1;
        int b0 = half*128 + wv*32;

        bf16x8 a[2][12];
        #pragma unroll
        for (int m=0;m<2;m++)
            #pragma unroll
            for (int kc=0;kc<12;kc++)
                a[m][kc] = *(const bf16x8*)(A + ((size_t)(b0+m*16+lr)*64 + t)*384 + kc*32 + lk*8);

        for (int jg=0; jg<16; jg++){
            {
                const bf16x8* src = (const bf16x8*)(pwih + (size_t)jg*48*512);
                bf16x8* dst = (bf16x8*)bsh;
                #pragma unroll
                for (int i=0;i<12;i++)
                    dst[tid + i*256] = src[tid + i*256];
            }
            __syncthreads();

            f32x4 acc[2][4];
            #pragma unroll
            for (int g=0; g<4; g++){
                float bias = b_ih[g*256 + jg*16 + lr];
                f32x4 v = {bias,bias,bias,bias};
                acc[0][g]=v; acc[1][g]=v;
            }
            #pragma unroll
            for (int kc=0; kc<12; kc++){
                bf16x8 b0v = *(const bf16x8*)(bsh + (size_t)((0*12+kc)*64+lane)*8);
                bf16x8 b1v = *(const bf16x8*)(bsh + (size_t)((1*12+kc)*64+lane)*8);
                bf16x8 b2v = *(const bf16x8*)(bsh + (size_t)((2*12+kc)*64+lane)*8);
                bf16x8 b3v = *(const bf16x8*)(bsh + (size_t)((3*12+kc)*64+lane)*8);
                #pragma unroll
                for (int m=0;m<2;m++){
                    acc[m][0] = MFMA(a[m][kc], b0v, acc[m][0]);
                    acc[m][1] = MFMA(a[m][kc], b1v, acc[m][1]);
                    acc[m][2] = MFMA(a[m][kc], b2v, acc[m][2]);
                    acc[m][3] = MFMA(a[m][kc], b3v, acc[m][3]);
                }
            }
            #pragma unroll
            for (int m=0;m<2;m++)
                #pragma unroll
                for (int r=0;r<4;r++){
                    int b = b0 + m*16 + lk*4 + r;
                    int trow = t*256 + b;
                    f32x4 pk;
                    pk[0] = acc[m][0][r]; pk[1] = acc[m][1][r];
                    pk[2] = acc[m][2][r]; pk[3] = acc[m][3][r];
                    st_f32x4_sys(xw + ((size_t)trow*256 + jg*16 + lr)*4, pk);
                }
            __syncthreads();
        }

        // completion: drain stores, then ordered counter update
        asm volatile("s_waitcnt vmcnt(0)" ::: "memory");
        __syncthreads();
        if (tid == 0){
            unsigned* cnt = &flags[2048 + half*128];
            while (__hip_atomic_load(cnt, __ATOMIC_RELAXED, __HIP_MEMORY_SCOPE_SYSTEM)
                   != (unsigned)t) {}
            __hip_atomic_store(cnt, (unsigned)(t+1),
                               __ATOMIC_RELAXED, __HIP_MEMORY_SCOPE_SYSTEM);
        }
        return;
    }

    // ================= LSTM =================
    int p = blk >> 1, hf = blk & 1;
    int bb0 = p*16;
    int jg0 = hf*8 + wv*2;

    bf16x8 bfr[2][4][8];
    #pragma unroll
    for (int jl=0;jl<2;jl++)
        #pragma unroll
        for (int g=0;g<4;g++)
            #pragma unroll
            for (int kc=0;kc<8;kc++)
                bfr[jl][g][kc] = *(const bf16x8*)(pwhh + (size_t)((((jg0+jl)*4+g)*8+kc)*64+lane)*8);

    float wdt0 = W_dt[jg0*16 + lr];
    float wdt1 = W_dt[(jg0+1)*16 + lr];

    float cst[2][4] = {{0.f,0.f,0.f,0.f},{0.f,0.f,0.f,0.f}};
    bf16x8 a[8];
    #pragma unroll
    for (int kc=0;kc<8;kc++) a[kc] = (bf16x8)(short)0;

    int bth = bb0 + lk*4;

    const unsigned* xcnt = &flags[2048 + ((p >= 8) ? 128 : 0)];
    unsigned seen = 0;

    // wait xw[0] ready
    while (seen < 1u){
        unsigned v = 0;
        if (lane == 0)
            v = __hip_atomic_load(xcnt, __ATOMIC_RELAXED, __HIP_MEMORY_SCOPE_SYSTEM);
        v = __shfl(v, 0);
        seen = v;
    }

    f32x4 xwn[2][4];
    #pragma unroll
    for (int jl=0;jl<2;jl++)
        #pragma unroll
        for (int r=0;r<4;r++)
            xwn[jl][r] = ld_f32x4_sys(xw + ((size_t)(bth+r)*256 + (jg0+jl)*16 + lr)*4);
    float4 dtn = *(const float4*)(dtv + bth);
    asm volatile("s_waitcnt vmcnt(0)" ::: "memory");

    // acc for t=0
    f32x4 acc[2][4];
    #pragma unroll
    for (int jl=0;jl<2;jl++){
        f32x4 v0, v1, v2, v3;
        #pragma unroll
        for (int r=0;r<4;r++){
            v0[r] = xwn[jl][r][0]; v1[r] = xwn[jl][r][1];
            v2[r] = xwn[jl][r][2]; v3[r] = xwn[jl][r][3];
        }
        acc[jl][0] = v0; acc[jl][1] = v1; acc[jl][2] = v2; acc[jl][3] = v3;
    }

    unsigned int* myflag   = &flags[blk*64];
    unsigned int* partflag = &flags[(blk^1)*64];

    for (int t=0; t<64; t++){
        asm volatile("s_waitcnt vmcnt(0)" ::: "memory");
        __builtin_amdgcn_sched_barrier(0);

        #pragma unroll
        for (int kc=0; kc<8; kc++){
            #pragma unroll
            for (int jl=0;jl<2;jl++){
                acc[jl][0] = MFMA(a[kc], bfr[jl][0][kc], acc[jl][0]);
                acc[jl][1] = MFMA(a[kc], bfr[jl][1][kc], acc[jl][1]);
                acc[jl][2] = MFMA(a[kc], bfr[jl][2][kc], acc[jl][2]);
                acc[jl][3] = MFMA(a[kc], bfr[jl][3][kc], acc[jl][3]);
            }
        }

        u16* hw = (t&1) ? hb1 : hb0;
        #pragma unroll
        for (int jl=0;jl<2;jl++){
            float wdt = jl ? wdt1 : wdt0;
            int jcol = (jg0+jl)*16 + lr;
            #pragma unroll
            for (int r=0;r<4;r++){
                float dd = (r==0)?dtn.x:(r==1)?dtn.y:(r==2)?dtn.z:dtn.w;
                float gi = sigm(acc[jl][0][r]);
                float gf = sigm(acc[jl][1][r] + wdt*dd);
                float gg = tanhfast(acc[jl][2][r]);
                float go = sigm(acc[jl][3][r]);
                float cn = fmaf(gf, cst[jl][r], gi*gg);
                cst[jl][r] = cn;
                float hv = go * tanhfast(cn);
                if (t < 63){
                    st_b16_sys(hw + (size_t)(bth+r)*256 + jcol, (unsigned)f2b(hv));
                } else {
                    hout[(size_t)(bth+r)*256 + jcol] = hv;
                    cout[(size_t)(bth+r)*256 + jcol] = cn;
                }
            }
        }

        if (t < 63){
            asm volatile("s_waitcnt vmcnt(0)" ::: "memory");
            __syncthreads();
            if (tid == 0)
                __hip_atomic_store(myflag, (unsigned)(t+1),
                                   __ATOMIC_RELAXED, __HIP_MEMORY_SCOPE_SYSTEM);

            // gate xw[t+1] readiness (steady state: seen==64, zero cost)
            while (seen < (unsigned)(t+2)){
                unsigned v = 0;
                if (lane == 0)
                    v = __hip_atomic_load(xcnt, __ATOMIC_RELAXED, __HIP_MEMORY_SCOPE_SYSTEM);
                v = __shfl(v, 0);
                seen = v;
            }

            // prefetch next xw/dt (sys loads; overlap the partner poll)
            #pragma unroll
            for (int jl=0;jl<2;jl++)
                #pragma unroll
                for (int r=0;r<4;r++)
                    xwn[jl][r] = ld_f32x4_sys(xw + ((size_t)((t+1)*256 + bth+r)*256 + (jg0+jl)*16 + lr)*4);
            dtn = *(const float4*)(dtv + (t+1)*256 + bth);

            if (lane == 0){
                while (__hip_atomic_load(partflag, __ATOMIC_RELAXED,
                                         __HIP_MEMORY_SCOPE_SYSTEM) < (unsigned)(t+1)) {}
            }
            __builtin_amdgcn_wave_barrier();

            const u16* hr = (t&1) ? hb1 : hb0;
            #pragma unroll
            for (int kc=0; kc<8; kc++)
                a[kc] = ld_b128_sys(hr + (size_t)(bb0+lr)*256 + kc*32 + lk*8);

            // build acc for t+1 in the h-load shadow (xwn drained by poll's use)
            asm volatile("s_waitcnt vmcnt(8)" ::: "memory");
            #pragma unroll
            for (int jl=0;jl<2;jl++){
                f32x4 v0, v1, v2, v3;
                #pragma unroll
                for (int r=0;r<4;r++){
                    v0[r] = xwn[jl][r][0]; v1[r] = xwn[jl][r][1];
                    v2[r] = xwn[jl][r][2]; v3[r] = xwn[jl][r][3];
                }
                acc[jl][0] = v0; acc[jl][1] = v1; acc[jl][2] = v2; acc[jl][3] = v3;
            }
        }
    }
}

// ---------------- heads (fp32) ----------------
__device__ __forceinline__ void dense30(
    const float* in, int istride,
    const float* __restrict__ W, int wstride, int K,
    const float* __restrict__ bias, const float* extra,
    float* outp, int ostride, bool relu, int j, int rh)
{
    float acc[15];
    #pragma unroll
    for (int i=0;i<15;i++) acc[i]=0.f;
    const float* w = W + j*wstride;
    for (int k=0;k<K;k+=4){
        float4 wv = *(const float4*)(w+k);
        #pragma unroll
        for (int i=0;i<15;i++){
            float4 xv = *(const float4*)(in + (rh+2*i)*istride + k);
            acc[i] = fmaf(wv.x,xv.x,acc[i]);
            acc[i] = fmaf(wv.y,xv.y,acc[i]);
            acc[i] = fmaf(wv.z,xv.z,acc[i]);
            acc[i] = fmaf(wv.w,xv.w,acc[i]);
        }
    }
    float bb = bias[j] + (extra ? extra[j] : 0.f);
    #pragma unroll
    for (int i=0;i<15;i++){
        float v = acc[i]+bb;
        outp[(rh+2*i)*ostride+j] = relu ? fmaxf(v,0.f) : v;
    }
}

__device__ __forceinline__ float dense1(
    const float* in, const float* __restrict__ W,
    const float* __restrict__ bias, int K, int j)
{
    const float* w = W + j*K;
    float s = 0.f;
    for (int k=0;k<K;k+=4){
        float4 wv = *(const float4*)(w+k);
        float4 xv = *(const float4*)(in+k);
        s = fmaf(wv.x,xv.x,s); s = fmaf(wv.y,xv.y,s);
        s = fmaf(wv.z,xv.z,s); s = fmaf(wv.w,xv.w,s);
    }
    return s + bias[j];
}

__global__ __launch_bounds__(256) void k_heads(
    const float* __restrict__ h, const float* __restrict__ cbuf,
    const float* __restrict__ rl,
    const float* __restrict__ a_w0, const float* __restrict__ a_b0,
    const float* __restrict__ a_w1, const float* __restrict__ a_b1,
    const float* __restrict__ c_w0, const float* __restrict__ c_b0,
    const float* __restrict__ c_w1, const float* __restrict__ c_b1,
    const float* __restrict__ log_std,
    float* __restrict__ out)
{
    __shared__ __align__(16) float hv[LH];
    __shared__ __align__(16) float rls[NR][HD];
    __shared__ __align__(16) float hid[NR][HD];
    __shared__ __align__(16) float dot2[HD];
    __shared__ __align__(16) float red[128];

    int b = blockIdx.x, tid = threadIdx.x;
    hv[tid] = h[b*LH + tid];
    for (int idx=tid; idx<NR*HD; idx+=256) rls[idx>>7][idx&127] = rl[(size_t)b*NR*HD + idx];
    __syncthreads();

    if (tid < 128){
        const float* w = a_w0 + tid*LIN + HD;
        float s = 0.f;
        for (int k=0;k<LH;k+=4){
            float4 wv = *(const float4*)(w+k);
            s = fmaf(wv.x,hv[k],s); s = fmaf(wv.y,hv[k+1],s);
            s = fmaf(wv.z,hv[k+2],s); s = fmaf(wv.w,hv[k+3],s);
        }
        dot2[tid] = s;
    }
    __syncthreads();

    int j = tid & 127, rh = tid >> 7;
    dense30(&rls[0][0], HD, a_w0, LIN, HD, a_b0, dot2, &hid[0][0], HD, true, j, rh);
    __syncthreads();

    if (tid < 60){
        int r = tid >> 1, o = tid & 1;
        const float* w = a_w1 + o*HD;
        float s = a_b1[o];
        for (int k=0;k<HD;k++) s = fmaf(hid[r][k], w[k], s);
        out[AM_OFF + b*60 + tid] = s;
        out[ALS_OFF + b*60 + tid] = log_std[tid];
    }

    float term = 0.f;
    if (tid < 128) term = fmaxf(dense1(hv, c_w0, c_b0, LH, tid), 0.f) * c_w1[tid];
    if (tid < 128) red[tid] = term;
    __syncthreads();
    for (int s2=64; s2>0; s2>>=1){
        if (tid < s2) red[tid] += red[tid+s2];
        __syncthreads();
    }
    if (tid == 0) out[V_OFF + b] = red[0] + c_b1[0];

    out[H_OFF + b*LH + tid] = hv[tid];
    out[C_OFF + b*LH + tid] = cbuf[b*LH + tid];
}

extern "C" void kernel_launch(void* const* d_in, const int* in_sizes, int n_in,
                              void* d_out, int out_size, void* d_ws, size_t ws_size,
                              hipStream_t stream)
{
    const float* obs   = (const float*)d_in[0];
    const float* re_w0 = (const float*)d_in[1];
    const float* re_b0 = (const float*)d_in[2];
    const float* re_w1 = (const float*)d_in[3];
    const float* re_b1 = (const float*)d_in[4];
    const float* re_w2 = (const float*)d_in[5];
    const float* re_b2 = (const float*)d_in[6];
    const float* me_w0 = (const float*)d_in[7];
    const float* me_b0 = (const float*)d_in[8];
    const float* me_w1 = (const float*)d_in[9];
    const float* me_b1 = (const float*)d_in[10];
    const float* me_w2 = (const float*)d_in[11];
    const float* me_b2 = (const float*)d_in[12];
    const float* W_ih  = (const float*)d_in[13];
    const float* b_ih  = (const float*)d_in[14];
    const float* W_hh  = (const float*)d_in[15];
    const float* W_dt  = (const float*)d_in[16];
    const float* a_w0  = (const float*)d_in[17];
    const float* a_b0  = (const float*)d_in[18];
    const float* a_w1  = (const float*)d_in[19];
    const float* a_b1  = (const float*)d_in[20];
    const float* c_w0  = (const float*)d_in[21];
    const float* c_b0  = (const float*)d_in[22];
    const float* c_w1  = (const float*)d_in[23];
    const float* c_b1  = (const float*)d_in[24];
    const float* lstd  = (const float*)d_in[25];
    float* out = (float*)d_out;

    float* ws = (float*)d_ws;
    size_t off = 0;
    float* xw4  = ws + off; off += (size_t)16384*1024;
    float* hout = ws + off; off += (size_t)Bn*LH;
    float* cb   = ws + off; off += (size_t)Bn*LH;
    float* rl   = ws + off; off += (size_t)Bn*NR*HD;
    float* dtv  = ws + off; off += (size_t)16384;
    unsigned int* flags = (unsigned int*)(ws + off); off += 2304;

    u16* us = (u16*)(ws + off);
    size_t uo = 0;
    u16* li_bf = us + uo; uo += (size_t)16384*LIN;
    u16* pw0   = us + uo; uo += 128*32;
    u16* pw1   = us + uo; uo += 128*128;
    u16* pw2   = us + uo; uo += 128*128;
    u16* pm0   = us + uo; uo += 128*64;
    u16* pm1   = us + uo; uo += 128*128;
    u16* pm2   = us + uo; uo += 128*128;
    u16* pwih  = us + uo; uo += (size_t)1024*384;
    u16* pwhh  = us + uo; uo += (size_t)1024*256;
    u16* hb0   = us + uo; uo += (size_t)Bn*LH;
    u16* hb1   = us + uo; uo += (size_t)Bn*LH;

    k_setup<<<2937, 256, 0, stream>>>(re_w0, pw0, re_w1, pw1, re_w2, pw2,
                                      me_w0, pm0, me_w1, pm1, me_w2, pm2,
                                      W_ih, pwih, W_hh, pwhh, obs, dtv, flags);

    k_embed_market<<<8704, 256, 0, stream>>>(obs,
                                      pw0, re_b0, pw1, re_b1, pw2, re_b2,
                                      pm0, me_b0, pm1, me_b1, pm2, me_b2,
                                      li_bf, rl);

    k_xwlstm<<<160, 256, 0, stream>>>(li_bf, pwih, b_ih, xw4,
                                      pwhh, W_dt, dtv, hb0, hb1,
                                      hout, cb, flags);

    k_heads<<<256, 256, 0, stream>>>(hout, cb, rl,
        a_w0, a_b0, a_w1, a_b1, c_w0, c_b0, c_w1, c_b1, lstd, out);
}

// Round 18
// 427.882 us; speedup vs baseline: 1.0859x; 1.0298x over previous
//
#include <hip/hip_runtime.h>
#include <hip/hip_bf16.h>
#include <math.h>

#define Bn 256
#define Tn 64
#define OBSD 1000
#define NR 30
#define HD 128
#define LH 256
#define LIN 384
#define TDI 26

#define AM_OFF 0
#define ALS_OFF 15360
#define V_OFF 30720
#define H_OFF 30976
#define C_OFF 96512

typedef unsigned short u16;
typedef short bf16x8 __attribute__((ext_vector_type(8)));
typedef float f32x4 __attribute__((ext_vector_type(4)));

__device__ __forceinline__ float sigm(float x){ return 1.f/(1.f+__expf(-x)); }
__device__ __forceinline__ float tanhfast(float x){
    float ax = fabsf(x);
    float e = __expf(2.f*ax);
    float t = 1.f - 2.f/(e+1.f);
    return copysignf(t, x);
}

__device__ __forceinline__ u16 f2b(float f){
    union { __hip_bfloat16 h; u16 u; } cv;
    cv.h = __float2bfloat16(f);
    return cv.u;
}

// system-coherent (L3) access helpers — proven r5 protocol
__device__ __forceinline__ bf16x8 ld_b128_sys(const u16* p){
    bf16x8 r;
    asm volatile("global_load_dwordx4 %0, %1, off sc0 sc1"
                 : "=v"(r) : "v"(p) : "memory");
    return r;
}
__device__ __forceinline__ void st_b16_sys(u16* p, unsigned v){
    asm volatile("global_store_short %0, %1, off sc0 sc1"
                 :: "v"(p), "v"(v) : "memory");
}
__device__ __forceinline__ f32x4 ld_f32x4_sys(const float* p){
    f32x4 r;
    asm volatile("global_load_dwordx4 %0, %1, off sc0 sc1"
                 : "=v"(r) : "v"(p) : "memory");
    return r;
}
__device__ __forceinline__ void st_f32x4_sys(float* p, f32x4 v){
    asm volatile("global_store_dwordx4 %0, %1, off sc0 sc1"
                 :: "v"(p), "v"(v) : "memory");
}

#define MFMA(a,b,c) __builtin_amdgcn_mfma_f32_16x16x32_bf16(a,b,c,0,0,0)

// ---------------- fused setup kernel (packs + dtv + flags) ----------------
__device__ __forceinline__ void pack_one(
    const float* __restrict__ src, u16* __restrict__ dst,
    int N, int K, int Kpad, int t)
{
    if (t >= N*Kpad) return;
    int j = t / Kpad, k = t - j*Kpad;
    float v = (k < K) ? src[j*K + k] : 0.f;
    int ntile = j>>4, jr = j&15, kc = k>>5, ko = k&31;
    int lane = ((ko>>3)<<4) | jr, elem = ko&7;
    int KC = Kpad>>5;
    dst[(size_t)(((ntile*KC + kc)*64) + lane)*8 + elem] = f2b(v);
}

__device__ __forceinline__ void pack_gi_one(
    const float* __restrict__ src, u16* __restrict__ dst, int K, int t)
{
    int KC = K >> 5;
    if (t >= 1024*K) return;
    int n = t / K, k = t - n*K;
    int nt = n>>4, jr = n&15;
    int jg = nt>>2, g = nt&3;
    float v = src[(size_t)(g*256 + jg*16 + jr)*K + k];
    int kc = k>>5, ko = k&31;
    int lane = ((ko>>3)<<4) | jr, e = ko&7;
    dst[(size_t)(((nt*KC + kc)*64) + lane)*8 + e] = f2b(v);
}

__global__ __launch_bounds__(256) void k_setup(
    const float* __restrict__ re_w0, u16* __restrict__ pw0,
    const float* __restrict__ re_w1, u16* __restrict__ pw1,
    const float* __restrict__ re_w2, u16* __restrict__ pw2,
    const float* __restrict__ me_w0, u16* __restrict__ pm0,
    const float* __restrict__ me_w1, u16* __restrict__ pm1,
    const float* __restrict__ me_w2, u16* __restrict__ pm2,
    const float* __restrict__ W_ih,  u16* __restrict__ pwih,
    const float* __restrict__ W_hh,  u16* __restrict__ pwhh,
    const float* __restrict__ obs,   float* __restrict__ dtv,
    unsigned int* __restrict__ flags)
{
    int blk = blockIdx.x, tid = threadIdx.x;
    if (blk < 16){            pack_one(re_w0, pw0, 128, 32, 32,  blk*256 + tid); }
    else if (blk < 80){       pack_one(re_w1, pw1, 128,128,128, (blk-16)*256 + tid); }
    else if (blk < 144){      pack_one(re_w2, pw2, 128,128,128, (blk-80)*256 + tid); }
    else if (blk < 176){      pack_one(me_w0, pm0, 128, 40, 64, (blk-144)*256 + tid); }
    else if (blk < 240){      pack_one(me_w1, pm1, 128,128,128, (blk-176)*256 + tid); }
    else if (blk < 304){      pack_one(me_w2, pm2, 128,128,128, (blk-240)*256 + tid); }
    else if (blk < 1840){     pack_gi_one(W_ih, pwih, 384, (blk-304)*256 + tid); }
    else if (blk < 2864){     pack_gi_one(W_hh, pwhh, 256, (blk-1840)*256 + tid); }
    else if (blk < 2928){
        int idx = (blk-2864)*256 + tid;      // 16384
        int b = idx >> 6, t = idx & 63;
        dtv[t*256 + b] = obs[(size_t)idx*OBSD + TDI];
    } else {
        flags[(blk-2928)*256 + tid] = 0u;    // 2304 entries (9 blocks)
    }
}

// ---------------- fused embed (2 bt/block, M=64) + market (32 rows/block) ----------------
__global__ __launch_bounds__(256) void k_embed_market(
    const float* __restrict__ obs,
    const u16* __restrict__ pw0, const float* __restrict__ re_b0,
    const u16* __restrict__ pw1, const float* __restrict__ re_b1,
    const u16* __restrict__ pw2, const float* __restrict__ re_b2,
    const u16* __restrict__ pm0, const float* __restrict__ me_b0,
    const u16* __restrict__ pm1, const float* __restrict__ me_b1,
    const u16* __restrict__ pm2, const float* __restrict__ me_b2,
    u16* __restrict__ li_bf, float* __restrict__ runner_last)
{
    __shared__ __align__(16) u16 smem[19968];
    __shared__ float bsf[384];

    int blk = blockIdx.x, tid = threadIdx.x;
    int lane = tid & 63, wv = tid >> 6;
    int lr = lane & 15, lk = lane >> 4;
    f32x4 zero = {0.f,0.f,0.f,0.f};

    if (blk < 8192){
        u16* xr   = smem;
        u16* act1 = smem + 2560;
        u16* act2 = smem + 11264;
        float* bs0 = bsf, *bs1 = bsf+128, *bs2 = bsf+256;

        int bt0 = blk*2;

        for (int idx=tid; idx<2048; idx+=256){
            int r = idx>>5, k = idx&31;
            int sb = r>>5, rr = r&31;
            const float* row = obs + (size_t)(bt0+sb)*OBSD;
            float v = 0.f;
            if (rr < 30) v = (k<24) ? row[30 + rr*24 + k] : row[760 + rr*8 + (k-24)];
            xr[r*40 + k] = f2b(v);
        }
        if (tid < 128){ bs0[tid]=re_b0[tid]; bs1[tid]=re_b1[tid]; bs2[tid]=re_b2[tid]; }
        __syncthreads();

        f32x4 d[4][2];

        {
            bf16x8 a0[4];
            #pragma unroll
            for (int m=0;m<4;m++) a0[m] = *(const bf16x8*)(xr + (m*16+lr)*40 + lk*8);
            #pragma unroll
            for (int ns=0; ns<2; ns++){
                int n = 2*wv + ns;
                bf16x8 b = *(const bf16x8*)(pw0 + (size_t)(n*64 + lane)*8);
                #pragma unroll
                for (int m=0;m<4;m++) d[m][ns] = MFMA(a0[m], b, zero);
            }
        }
        #pragma unroll
        for (int m=0;m<4;m++)
            #pragma unroll
            for (int ns=0;ns<2;ns++){
                int col = (2*wv+ns)*16 + lr;
                float bias = bs0[col];
                #pragma unroll
                for (int r=0;r<4;r++)
                    act1[(m*16+lk*4+r)*136 + col] = f2b(fmaxf(d[m][ns][r] + bias, 0.f));
            }
        __syncthreads();

        #pragma unroll
        for (int m=0;m<4;m++)
            #pragma unroll
            for (int ns=0;ns<2;ns++) d[m][ns] = zero;
        #pragma unroll
        for (int kc=0; kc<4; kc++){
            bf16x8 am[4];
            #pragma unroll
            for (int m=0;m<4;m++) am[m] = *(const bf16x8*)(act1 + (m*16+lr)*136 + kc*32 + lk*8);
            #pragma unroll
            for (int ns=0; ns<2; ns++){
                int n = 2*wv + ns;
                bf16x8 b = *(const bf16x8*)(pw1 + (size_t)((n*4 + kc)*64 + lane)*8);
                #pragma unroll
                for (int m=0;m<4;m++) d[m][ns] = MFMA(am[m], b, d[m][ns]);
            }
        }
        #pragma unroll
        for (int m=0;m<4;m++)
            #pragma unroll
            for (int ns=0;ns<2;ns++){
                int col = (2*wv+ns)*16 + lr;
                float bias = bs1[col];
                #pragma unroll
                for (int r=0;r<4;r++)
                    act2[(m*16+lk*4+r)*136 + col] = f2b(fmaxf(d[m][ns][r] + bias, 0.f));
            }
        __syncthreads();

        #pragma unroll
        for (int m=0;m<4;m++)
            #pragma unroll
            for (int ns=0;ns<2;ns++) d[m][ns] = zero;
        #pragma unroll
        for (int kc=0; kc<4; kc++){
            bf16x8 am[4];
            #pragma unroll
            for (int m=0;m<4;m++) am[m] = *(const bf16x8*)(act2 + (m*16+lr)*136 + kc*32 + lk*8);
            #pragma unroll
            for (int ns=0; ns<2; ns++){
                int n = 2*wv + ns;
                bf16x8 b = *(const bf16x8*)(pw2 + (size_t)((n*4 + kc)*64 + lane)*8);
                #pragma unroll
                for (int m=0;m<4;m++) d[m][ns] = MFMA(am[m], b, d[m][ns]);
            }
        }

        u16* li0 = li_bf + (size_t)bt0*LIN;
        u16* li1 = li_bf + (size_t)(bt0+1)*LIN;
        bool last1 = (((bt0+1) & 63) == 63);
        int bb1 = (bt0+1) >> 6;

        #pragma unroll
        for (int ns=0; ns<2; ns++){
            int col = (2*wv+ns)*16 + lr;
            float bias = bs2[col];
            float vals[4][4];
            float s0=0.f, m0=-3.4e38f, s1=0.f, m1=-3.4e38f;
            #pragma unroll
            for (int m=0;m<4;m++)
                #pragma unroll
                for (int r=0;r<4;r++){
                    int rw = m*16 + lk*4 + r;
                    float v = d[m][ns][r] + bias;
                    vals[m][r] = v;
                    if (m < 2){
                        bool ok = rw < 30;
                        s0 += ok ? v : 0.f;
                        m0 = fmaxf(m0, ok ? v : -3.4e38f);
                    } else {
                        bool ok = (rw-32) < 30;
                        s1 += ok ? v : 0.f;
                        m1 = fmaxf(m1, ok ? v : -3.4e38f);
                    }
                }
            s0 += __shfl_xor(s0, 16); s0 += __shfl_xor(s0, 32);
            m0 = fmaxf(m0, __shfl_xor(m0, 16)); m0 = fmaxf(m0, __shfl_xor(m0, 32));
            s1 += __shfl_xor(s1, 16); s1 += __shfl_xor(s1, 32);
            m1 = fmaxf(m1, __shfl_xor(m1, 16)); m1 = fmaxf(m1, __shfl_xor(m1, 32));
            if (lk == 0){
                li0[128 + col] = f2b(s0 * (1.0f/30.0f));
                li0[256 + col] = f2b(m0);
            }
            if (lk == 1){
                li1[128 + col] = f2b(s1 * (1.0f/30.0f));
                li1[256 + col] = f2b(m1);
            }
            if (last1){
                #pragma unroll
                for (int m=2;m<4;m++)
                    #pragma unroll
                    for (int r=0;r<4;r++){
                        int rw = m*16 + lk*4 + r - 32;
                        if (rw < 30) runner_last[(size_t)bb1*3840 + rw*128 + col] = vals[m][r];
                    }
            }
        }
    } else {
        u16* xm  = smem;
        u16* ma1 = smem + 2304;
        u16* ma2 = smem + 6656;
        float* bs0 = bsf, *bs1 = bsf+128, *bs2 = bsf+256;

        int bt0 = (blk - 8192)*32;
        for (int idx=tid; idx<2048; idx+=256){
            int r = idx>>6, k = idx&63;
            const float* row = obs + (size_t)(bt0+r)*OBSD;
            float v = 0.f;
            if (k < 30) v = row[k];
            else if (k < 40) v = row[720 + k];
            xm[r*72 + k] = f2b(v);
        }
        if (tid < 128){ bs0[tid]=me_b0[tid]; bs1[tid]=me_b1[tid]; bs2[tid]=me_b2[tid]; }
        __syncthreads();

        f32x4 d[2][2];

        #pragma unroll
        for (int m=0;m<2;m++)
            #pragma unroll
            for (int ns=0;ns<2;ns++) d[m][ns] = zero;
        #pragma unroll
        for (int kc=0; kc<2; kc++){
            bf16x8 a0 = *(const bf16x8*)(xm + lr*72      + kc*32 + lk*8);
            bf16x8 a1 = *(const bf16x8*)(xm + (16+lr)*72 + kc*32 + lk*8);
            #pragma unroll
            for (int ns=0; ns<2; ns++){
                int n = 2*wv + ns;
                bf16x8 b = *(const bf16x8*)(pm0 + (size_t)((n*2 + kc)*64 + lane)*8);
                d[0][ns] = MFMA(a0, b, d[0][ns]);
                d[1][ns] = MFMA(a1, b, d[1][ns]);
            }
        }
        #pragma unroll
        for (int m=0;m<2;m++)
            #pragma unroll
            for (int ns=0;ns<2;ns++){
                int col = (2*wv+ns)*16 + lr;
                float bias = bs0[col];
                #pragma unroll
                for (int r=0;r<4;r++){
                    int rw = m*16 + lk*4 + r;
                    ma1[rw*136 + col] = f2b(fmaxf(d[m][ns][r] + bias, 0.f));
                }
            }
        __syncthreads();

        #pragma unroll
        for (int m=0;m<2;m++)
            #pragma unroll
            for (int ns=0;ns<2;ns++) d[m][ns] = zero;
        #pragma unroll
        for (int kc=0; kc<4; kc++){
            bf16x8 a0 = *(const bf16x8*)(ma1 + lr*136      + kc*32 + lk*8);
            bf16x8 a1 = *(const bf16x8*)(ma1 + (16+lr)*136 + kc*32 + lk*8);
            #pragma unroll
            for (int ns=0; ns<2; ns++){
                int n = 2*wv + ns;
                bf16x8 b = *(const bf16x8*)(pm1 + (size_t)((n*4 + kc)*64 + lane)*8);
                d[0][ns] = MFMA(a0, b, d[0][ns]);
                d[1][ns] = MFMA(a1, b, d[1][ns]);
            }
        }
        #pragma unroll
        for (int m=0;m<2;m++)
            #pragma unroll
            for (int ns=0;ns<2;ns++){
                int col = (2*wv+ns)*16 + lr;
                float bias = bs1[col];
                #pragma unroll
                for (int r=0;r<4;r++){
                    int rw = m*16 + lk*4 + r;
                    ma2[rw*136 + col] = f2b(fmaxf(d[m][ns][r] + bias, 0.f));
                }
            }
        __syncthreads();

        #pragma unroll
        for (int m=0;m<2;m++)
            #pragma unroll
            for (int ns=0;ns<2;ns++) d[m][ns] = zero;
        #pragma unroll
        for (int kc=0; kc<4; kc++){
            bf16x8 a0 = *(const bf16x8*)(ma2 + lr*136      + kc*32 + lk*8);
            bf16x8 a1 = *(const bf16x8*)(ma2 + (16+lr)*136 + kc*32 + lk*8);
            #pragma unroll
            for (int ns=0; ns<2; ns++){
                int n = 2*wv + ns;
                bf16x8 b = *(const bf16x8*)(pm2 + (size_t)((n*4 + kc)*64 + lane)*8);
                d[0][ns] = MFMA(a0, b, d[0][ns]);
                d[1][ns] = MFMA(a1, b, d[1][ns]);
            }
        }
        #pragma unroll
        for (int m=0;m<2;m++)
            #pragma unroll
            for (int ns=0;ns<2;ns++){
                int col = (2*wv+ns)*16 + lr;
                float bias = bs2[col];
                #pragma unroll
                for (int r=0;r<4;r++){
                    int rw = m*16 + lk*4 + r;
                    li_bf[(size_t)(bt0+rw)*LIN + col] = f2b(d[m][ns][r] + bias);
                }
            }
    }
}

// ---------------- fused xw producers + LSTM + actor-partial producers ----------------
// blocks 0..31: LSTM pairs; 32..159: xw producers (t-major);
// 160..191: rlpart producers (A0r @ runner_last + a_b0), plain stores —
// consumer is k_heads (next dispatch; kernel-boundary coherence).
__global__ __launch_bounds__(256,1) void k_xwlstm(
    const u16* __restrict__ A, const u16* __restrict__ pwih,
    const float* __restrict__ b_ih, float* __restrict__ xw,
    const u16* __restrict__ pwhh, const float* __restrict__ W_dt,
    const float* __restrict__ dtv,
    u16* __restrict__ hb0, u16* __restrict__ hb1,
    float* __restrict__ hout, float* __restrict__ cout,
    unsigned int* __restrict__ flags,
    const float* __restrict__ a_w0, const float* __restrict__ a_b0,
    const float* __restrict__ runner_last, float* __restrict__ rlp)
{
    __shared__ __align__(16) u16 bsh[48*512];   // xw path; rlpart reuses as float

    int blk = blockIdx.x;
    int tid = threadIdx.x;
    int lane = tid & 63, wv = tid >> 6;
    int lr = lane & 15, lk = lane >> 4;

    if (blk >= 160){
        // ================= actor-partial producer =================
        int pb = blk - 160;       // 0..31
        int b0p = pb*8;
        float* rlsf = (float*)bsh;    // 3840 floats = 15KB
        for (int bi=0; bi<8; bi++){
            int b = b0p + bi;
            for (int idx=tid; idx<3840; idx+=256)
                rlsf[idx] = runner_last[(size_t)b*3840 + idx];
            __syncthreads();
            int j = tid & 127, rh = tid >> 7;
            #pragma unroll
            for (int i=0;i<15;i++){
                int r = rh + 2*i;
                const float* w = a_w0 + (size_t)j*LIN;
                const float* x = rlsf + r*128;
                float s = 0.f;
                for (int k=0;k<128;k+=4){
                    float4 wv4 = *(const float4*)(w+k);
                    float4 xv4 = *(const float4*)(x+k);
                    s = fmaf(wv4.x,xv4.x,s); s = fmaf(wv4.y,xv4.y,s);
                    s = fmaf(wv4.z,xv4.z,s); s = fmaf(wv4.w,xv4.w,s);
                }
                rlp[(size_t)b*3840 + r*128 + j] = s + a_b0[j];
            }
            __syncthreads();
        }
        return;
    }

    if (blk >= 32){
        // ================= xw producer =================
        int tb = blk - 32;
        int t = tb >> 1, half = tb & 1;
        int b0 = half*128 + wv*32;

        bf16x8 a[2][12];
        #pragma unroll
        for (int m=0;m<2;m++)
            #pragma unroll
            for (int kc=0;kc<12;kc++)
                a[m][kc] = *(const bf16x8*)(A + ((size_t)(b0+m*16+lr)*64 + t)*384 + kc*32 + lk*8);

        for (int jg=0; jg<16; jg++){
            {
                const bf16x8* src = (const bf16x8*)(pwih + (size_t)jg*48*512);
                bf16x8* dst = (bf16x8*)bsh;
                #pragma unroll
                for (int i=0;i<12;i++)
                    dst[tid + i*256] = src[tid + i*256];
            }
            __syncthreads();

            f32x4 acc[2][4];
            #pragma unroll
            for (int g=0; g<4; g++){
                float bias = b_ih[g*256 + jg*16 + lr];
                f32x4 v = {bias,bias,bias,bias};
                acc[0][g]=v; acc[1][g]=v;
            }
            #pragma unroll
            for (int kc=0; kc<12; kc++){
                bf16x8 b0v = *(const bf16x8*)(bsh + (size_t)((0*12+kc)*64+lane)*8);
                bf16x8 b1v = *(const bf16x8*)(bsh + (size_t)((1*12+kc)*64+lane)*8);
                bf16x8 b2v = *(const bf16x8*)(bsh + (size_t)((2*12+kc)*64+lane)*8);
                bf16x8 b3v = *(const bf16x8*)(bsh + (size_t)((3*12+kc)*64+lane)*8);
                #pragma unroll
                for (int m=0;m<2;m++){
                    acc[m][0] = MFMA(a[m][kc], b0v, acc[m][0]);
                    acc[m][1] = MFMA(a[m][kc], b1v, acc[m][1]);
                    acc[m][2] = MFMA(a[m][kc], b2v, acc[m][2]);
                    acc[m][3] = MFMA(a[m][kc], b3v, acc[m][3]);
                }
            }
            #pragma unroll
            for (int m=0;m<2;m++)
                #pragma unroll
                for (int r=0;r<4;r++){
                    int b = b0 + m*16 + lk*4 + r;
                    int trow = t*256 + b;
                    f32x4 pk;
                    pk[0] = acc[m][0][r]; pk[1] = acc[m][1][r];
                    pk[2] = acc[m][2][r]; pk[3] = acc[m][3][r];
                    st_f32x4_sys(xw + ((size_t)trow*256 + jg*16 + lr)*4, pk);
                }
            __syncthreads();
        }

        asm volatile("s_waitcnt vmcnt(0)" ::: "memory");
        __syncthreads();
        if (tid == 0){
            unsigned* cnt = &flags[2048 + half*128];
            while (__hip_atomic_load(cnt, __ATOMIC_RELAXED, __HIP_MEMORY_SCOPE_SYSTEM)
                   != (unsigned)t) {}
            __hip_atomic_store(cnt, (unsigned)(t+1),
                               __ATOMIC_RELAXED, __HIP_MEMORY_SCOPE_SYSTEM);
        }
        return;
    }

    // ================= LSTM =================
    int p = blk >> 1, hf = blk & 1;
    int bb0 = p*16;
    int jg0 = hf*8 + wv*2;

    bf16x8 bfr[2][4][8];
    #pragma unroll
    for (int jl=0;jl<2;jl++)
        #pragma unroll
        for (int g=0;g<4;g++)
            #pragma unroll
            for (int kc=0;kc<8;kc++)
                bfr[jl][g][kc] = *(const bf16x8*)(pwhh + (size_t)((((jg0+jl)*4+g)*8+kc)*64+lane)*8);

    float wdt0 = W_dt[jg0*16 + lr];
    float wdt1 = W_dt[(jg0+1)*16 + lr];

    float cst[2][4] = {{0.f,0.f,0.f,0.f},{0.f,0.f,0.f,0.f}};
    bf16x8 a[8];
    #pragma unroll
    for (int kc=0;kc<8;kc++) a[kc] = (bf16x8)(short)0;

    int bth = bb0 + lk*4;

    const unsigned* xcnt = &flags[2048 + ((p >= 8) ? 128 : 0)];
    unsigned seen = 0;

    // wait xw[0] ready
    while (seen < 1u){
        unsigned v = 0;
        if (lane == 0)
            v = __hip_atomic_load(xcnt, __ATOMIC_RELAXED, __HIP_MEMORY_SCOPE_SYSTEM);
        v = __shfl(v, 0);
        seen = v;
    }

    f32x4 xwn[2][4];
    #pragma unroll
    for (int jl=0;jl<2;jl++)
        #pragma unroll
        for (int r=0;r<4;r++)
            xwn[jl][r] = ld_f32x4_sys(xw + ((size_t)(bth+r)*256 + (jg0+jl)*16 + lr)*4);
    float4 dtn = *(const float4*)(dtv + bth);
    asm volatile("s_waitcnt vmcnt(0)" ::: "memory");

    // acc for t=0
    f32x4 acc[2][4];
    #pragma unroll
    for (int jl=0;jl<2;jl++){
        f32x4 v0, v1, v2, v3;
        #pragma unroll
        for (int r=0;r<4;r++){
            v0[r] = xwn[jl][r][0]; v1[r] = xwn[jl][r][1];
            v2[r] = xwn[jl][r][2]; v3[r] = xwn[jl][r][3];
        }
        acc[jl][0] = v0; acc[jl][1] = v1; acc[jl][2] = v2; acc[jl][3] = v3;
    }

    unsigned int* myflag   = &flags[blk*64];
    unsigned int* partflag = &flags[(blk^1)*64];

    for (int t=0; t<64; t++){
        asm volatile("s_waitcnt vmcnt(0)" ::: "memory");
        __builtin_amdgcn_sched_barrier(0);

        #pragma unroll
        for (int kc=0; kc<8; kc++){
            #pragma unroll
            for (int jl=0;jl<2;jl++){
                acc[jl][0] = MFMA(a[kc], bfr[jl][0][kc], acc[jl][0]);
                acc[jl][1] = MFMA(a[kc], bfr[jl][1][kc], acc[jl][1]);
                acc[jl][2] = MFMA(a[kc], bfr[jl][2][kc], acc[jl][2]);
                acc[jl][3] = MFMA(a[kc], bfr[jl][3][kc], acc[jl][3]);
            }
        }

        u16* hw = (t&1) ? hb1 : hb0;
        #pragma unroll
        for (int jl=0;jl<2;jl++){
            float wdt = jl ? wdt1 : wdt0;
            int jcol = (jg0+jl)*16 + lr;
            #pragma unroll
            for (int r=0;r<4;r++){
                float dd = (r==0)?dtn.x:(r==1)?dtn.y:(r==2)?dtn.z:dtn.w;
                float gi = sigm(acc[jl][0][r]);
                float gf = sigm(acc[jl][1][r] + wdt*dd);
                float gg = tanhfast(acc[jl][2][r]);
                float go = sigm(acc[jl][3][r]);
                float cn = fmaf(gf, cst[jl][r], gi*gg);
                cst[jl][r] = cn;
                float hv = go * tanhfast(cn);
                if (t < 63){
                    st_b16_sys(hw + (size_t)(bth+r)*256 + jcol, (unsigned)f2b(hv));
                } else {
                    hout[(size_t)(bth+r)*256 + jcol] = hv;
                    cout[(size_t)(bth+r)*256 + jcol] = cn;
                }
            }
        }

        if (t < 63){
            asm volatile("s_waitcnt vmcnt(0)" ::: "memory");
            __syncthreads();
            if (tid == 0)
                __hip_atomic_store(myflag, (unsigned)(t+1),
                                   __ATOMIC_RELAXED, __HIP_MEMORY_SCOPE_SYSTEM);

            // gate xw[t+1] readiness (steady state: seen==64, zero cost)
            while (seen < (unsigned)(t+2)){
                unsigned v = 0;
                if (lane == 0)
                    v = __hip_atomic_load(xcnt, __ATOMIC_RELAXED, __HIP_MEMORY_SCOPE_SYSTEM);
                v = __shfl(v, 0);
                seen = v;
            }

            // prefetch next xw/dt (sys loads; overlap the partner poll)
            #pragma unroll
            for (int jl=0;jl<2;jl++)
                #pragma unroll
                for (int r=0;r<4;r++)
                    xwn[jl][r] = ld_f32x4_sys(xw + ((size_t)((t+1)*256 + bth+r)*256 + (jg0+jl)*16 + lr)*4);
            dtn = *(const float4*)(dtv + (t+1)*256 + bth);

            if (lane == 0){
                while (__hip_atomic_load(partflag, __ATOMIC_RELAXED,
                                         __HIP_MEMORY_SCOPE_SYSTEM) < (unsigned)(t+1)) {}
            }
            __builtin_amdgcn_wave_barrier();

            const u16* hr = (t&1) ? hb1 : hb0;
            #pragma unroll
            for (int kc=0; kc<8; kc++)
                a[kc] = ld_b128_sys(hr + (size_t)(bb0+lr)*256 + kc*32 + lk*8);

            // build acc for t+1 in the h-load shadow
            asm volatile("s_waitcnt vmcnt(8)" ::: "memory");
            #pragma unroll
            for (int jl=0;jl<2;jl++){
                f32x4 v0, v1, v2, v3;
                #pragma unroll
                for (int r=0;r<4;r++){
                    v0[r] = xwn[jl][r][0]; v1[r] = xwn[jl][r][1];
                    v2[r] = xwn[jl][r][2]; v3[r] = xwn[jl][r][3];
                }
                acc[jl][0] = v0; acc[jl][1] = v1; acc[jl][2] = v2; acc[jl][3] = v3;
            }
        }
    }
}

// ---------------- heads (fp32, rlpart-precomputed) ----------------
__device__ __forceinline__ float dense1(
    const float* in, const float* __restrict__ W,
    const float* __restrict__ bias, int K, int j)
{
    const float* w = W + j*K;
    float s = 0.f;
    for (int k=0;k<K;k+=4){
        float4 wv = *(const float4*)(w+k);
        float4 xv = *(const float4*)(in+k);
        s = fmaf(wv.x,xv.x,s); s = fmaf(wv.y,xv.y,s);
        s = fmaf(wv.z,xv.z,s); s = fmaf(wv.w,xv.w,s);
    }
    return s + bias[j];
}

__global__ __launch_bounds__(256) void k_heads(
    const float* __restrict__ h, const float* __restrict__ cbuf,
    const float* __restrict__ rlp,
    const float* __restrict__ a_w0,
    const float* __restrict__ a_w1, const float* __restrict__ a_b1,
    const float* __restrict__ c_w0, const float* __restrict__ c_b0,
    const float* __restrict__ c_w1, const float* __restrict__ c_b1,
    const float* __restrict__ log_std,
    float* __restrict__ out)
{
    __shared__ __align__(16) float hv[LH];
    __shared__ __align__(16) float hid[NR][HD];
    __shared__ __align__(16) float dot2[HD];
    __shared__ __align__(16) float red[128];

    int b = blockIdx.x, tid = threadIdx.x;
    hv[tid] = h[b*LH + tid];
    __syncthreads();

    if (tid < 128){
        const float* w = a_w0 + tid*LIN + HD;
        float s = 0.f;
        for (int k=0;k<LH;k+=4){
            float4 wv = *(const float4*)(w+k);
            s = fmaf(wv.x,hv[k],s); s = fmaf(wv.y,hv[k+1],s);
            s = fmaf(wv.z,hv[k+2],s); s = fmaf(wv.w,hv[k+3],s);
        }
        dot2[tid] = s;
    }
    __syncthreads();

    // hid = relu(rlpart + dot2)
    for (int idx=tid; idx<NR*HD; idx+=256){
        float v = rlp[(size_t)b*3840 + idx] + dot2[idx & 127];
        hid[idx>>7][idx&127] = fmaxf(v, 0.f);
    }
    __syncthreads();

    if (tid < 60){
        int r = tid >> 1, o = tid & 1;
        const float* w = a_w1 + o*HD;
        float s = a_b1[o];
        for (int k=0;k<HD;k++) s = fmaf(hid[r][k], w[k], s);
        out[AM_OFF + b*60 + tid] = s;
        out[ALS_OFF + b*60 + tid] = log_std[tid];
    }

    float term = 0.f;
    if (tid < 128) term = fmaxf(dense1(hv, c_w0, c_b0, LH, tid), 0.f) * c_w1[tid];
    if (tid < 128) red[tid] = term;
    __syncthreads();
    for (int s2=64; s2>0; s2>>=1){
        if (tid < s2) red[tid] += red[tid+s2];
        __syncthreads();
    }
    if (tid == 0) out[V_OFF + b] = red[0] + c_b1[0];

    out[H_OFF + b*LH + tid] = hv[tid];
    out[C_OFF + b*LH + tid] = cbuf[b*LH + tid];
}

extern "C" void kernel_launch(void* const* d_in, const int* in_sizes, int n_in,
                              void* d_out, int out_size, void* d_ws, size_t ws_size,
                              hipStream_t stream)
{
    const float* obs   = (const float*)d_in[0];
    const float* re_w0 = (const float*)d_in[1];
    const float* re_b0 = (const float*)d_in[2];
    const float* re_w1 = (const float*)d_in[3];
    const float* re_b1 = (const float*)d_in[4];
    const float* re_w2 = (const float*)d_in[5];
    const float* re_b2 = (const float*)d_in[6];
    const float* me_w0 = (const float*)d_in[7];
    const float* me_b0 = (const float*)d_in[8];
    const float* me_w1 = (const float*)d_in[9];
    const float* me_b1 = (const float*)d_in[10];
    const float* me_w2 = (const float*)d_in[11];
    const float* me_b2 = (const float*)d_in[12];
    const float* W_ih  = (const float*)d_in[13];
    const float* b_ih  = (const float*)d_in[14];
    const float* W_hh  = (const float*)d_in[15];
    const float* W_dt  = (const float*)d_in[16];
    const float* a_w0  = (const float*)d_in[17];
    const float* a_b0  = (const float*)d_in[18];
    const float* a_w1  = (const float*)d_in[19];
    const float* a_b1  = (const float*)d_in[20];
    const float* c_w0  = (const float*)d_in[21];
    const float* c_b0  = (const float*)d_in[22];
    const float* c_w1  = (const float*)d_in[23];
    const float* c_b1  = (const float*)d_in[24];
    const float* lstd  = (const float*)d_in[25];
    float* out = (float*)d_out;

    float* ws = (float*)d_ws;
    size_t off = 0;
    float* xw4  = ws + off; off += (size_t)16384*1024;
    float* hout = ws + off; off += (size_t)Bn*LH;
    float* cb   = ws + off; off += (size_t)Bn*LH;
    float* rl   = ws + off; off += (size_t)Bn*NR*HD;
    float* rlp  = ws + off; off += (size_t)Bn*NR*HD;
    float* dtv  = ws + off; off += (size_t)16384;
    unsigned int* flags = (unsigned int*)(ws + off); off += 2304;

    u16* us = (u16*)(ws + off);
    size_t uo = 0;
    u16* li_bf = us + uo; uo += (size_t)16384*LIN;
    u16* pw0   = us + uo; uo += 128*32;
    u16* pw1   = us + uo; uo += 128*128;
    u16* pw2   = us + uo; uo += 128*128;
    u16* pm0   = us + uo; uo += 128*64;
    u16* pm1   = us + uo; uo += 128*128;
    u16* pm2   = us + uo; uo += 128*128;
    u16* pwih  = us + uo; uo += (size_t)1024*384;
    u16* pwhh  = us + uo; uo += (size_t)1024*256;
    u16* hb0   = us + uo; uo += (size_t)Bn*LH;
    u16* hb1   = us + uo; uo += (size_t)Bn*LH;

    k_setup<<<2937, 256, 0, stream>>>(re_w0, pw0, re_w1, pw1, re_w2, pw2,
                                      me_w0, pm0, me_w1, pm1, me_w2, pm2,
                                      W_ih, pwih, W_hh, pwhh, obs, dtv, flags);

    k_embed_market<<<8704, 256, 0, stream>>>(obs,
                                      pw0, re_b0, pw1, re_b1, pw2, re_b2,
                                      pm0, me_b0, pm1, me_b1, pm2, me_b2,
                                      li_bf, rl);

    k_xwlstm<<<192, 256, 0, stream>>>(li_bf, pwih, b_ih, xw4,
                                      pwhh, W_dt, dtv, hb0, hb1,
                                      hout, cb, flags,
                                      a_w0, a_b0, rl, rlp);

    k_heads<<<256, 256, 0, stream>>>(hout, cb, rlp,
        a_w0, a_w1, a_b1, c_w0, c_b0, c_w1, c_b1, lstd, out);
}